// Round 1
// baseline (762.151 us; speedup 1.0000x reference)
//
#include <hip/hip_runtime.h>
#include <hip/hip_bf16.h>
#include <stdint.h>

// EncoderLayer on MI355X: bf16 MFMA GEMMs + fp32 softmax/LN epilogues.
// Pipeline: prep(convert/transpose) -> QKV -> Vt -> flash(scores+softmax+PV,
//           writes exact attn) -> Wo+resid -> LN1 -> FFN1(relu) -> FFN2+resid -> LN2.

using bf16_t  = __hip_bfloat16;
using short8  = __attribute__((ext_vector_type(8))) short;
using short4v = __attribute__((ext_vector_type(4))) short;
using f32x4   = __attribute__((ext_vector_type(4))) float;

#define DEV static __device__ __forceinline__

DEV short bfbits(float f) {
  bf16_t h = __float2bfloat16(f);
  union { bf16_t h; short s; } u; u.h = h; return u.s;
}

// ---------------- elementwise fp32 -> bf16 (4 elems/thread) ----------------
__global__ __launch_bounds__(256) void k_f32_to_bf16(const float* __restrict__ in,
                                                     bf16_t* __restrict__ out) {
  size_t i = ((size_t)blockIdx.x * 256 + threadIdx.x) * 4;
  f32x4 x = *(const f32x4*)(in + i);
  short4v o;
  o[0] = bfbits(x[0]); o[1] = bfbits(x[1]); o[2] = bfbits(x[2]); o[3] = bfbits(x[3]);
  *(short4v*)((short*)out + i) = o;
}

// ---------------- transpose fp32 [R][C] -> bf16 [C][R] ----------------
__global__ __launch_bounds__(256) void k_transpose_f32_bf16(const float* __restrict__ in,
                                                            bf16_t* __restrict__ out,
                                                            int R, int C) {
  __shared__ float tile[32][33];
  int tx = threadIdx.x & 31, ty = threadIdx.x >> 5;   // 32 x 8
  int r0 = blockIdx.y * 32, c0 = blockIdx.x * 32;
  #pragma unroll
  for (int i = 0; i < 4; ++i)
    tile[ty + i * 8][tx] = in[(size_t)(r0 + ty + i * 8) * C + c0 + tx];
  __syncthreads();
  #pragma unroll
  for (int i = 0; i < 4; ++i)
    out[(size_t)(c0 + ty + i * 8) * R + r0 + tx] = __float2bfloat16(tile[tx][ty + i * 8]);
}

// ---------------- batched transpose bf16 [R][C] -> [C][R] ----------------
__global__ __launch_bounds__(256) void k_transpose_bf16_b(const bf16_t* __restrict__ in,
                                                          bf16_t* __restrict__ out,
                                                          int R, int C, long sIn, long sOut) {
  __shared__ bf16_t tile[32][33];
  const bf16_t* inz = in + (size_t)blockIdx.z * sIn;
  bf16_t* outz = out + (size_t)blockIdx.z * sOut;
  int tx = threadIdx.x & 31, ty = threadIdx.x >> 5;
  int r0 = blockIdx.y * 32, c0 = blockIdx.x * 32;
  #pragma unroll
  for (int i = 0; i < 4; ++i)
    tile[ty + i * 8][tx] = inz[(size_t)(r0 + ty + i * 8) * C + c0 + tx];
  __syncthreads();
  #pragma unroll
  for (int i = 0; i < 4; ++i)
    outz[(size_t)(c0 + ty + i * 8) * R + r0 + tx] = tile[tx][ty + i * 8];
}

// ---------------- GEMM: C[M][N] = A[M][K](bf16 or f32) @ Bt[N][K](bf16) ----------------
// Block 256 thr = 4 waves (2x2), wave tile (BM/2)x(BN/2), MFMA 16x16x32 bf16.
// A-frag: A[m=lane&15][k=(lane>>4)*8+j]; B-frag symmetric on Bt; C/D: col=lane&15,
// row=(lane>>4)*4+reg  [verified layouts per cdna_hip_programming.md §3].
template<int BM, int BN, bool AF32, bool ALPHA, bool BIAS, bool RELU, bool RESID,
         bool OUTF, bool OUTB>
__global__ __launch_bounds__(256)
void k_gemm_bt(const void* __restrict__ Ap, const bf16_t* __restrict__ Btp,
               float* __restrict__ Cf, bf16_t* __restrict__ Cb,
               const float* __restrict__ bias, const float* __restrict__ resid,
               int Kdim, int lda, int ldb, int ldc, float alpha,
               long strA, long strB, long strC) {
  constexpr int BK = 32, LDSK = 40;  // +8 bf16 pad: 80B rows, 16B-aligned, conflict-lite
  constexpr int WTM = BM / 2, WTN = BN / 2;
  constexpr int MI = WTM / 16, NI = WTN / 16;
  __shared__ __align__(16) bf16_t sA[BM][LDSK];
  __shared__ __align__(16) bf16_t sB[BN][LDSK];

  const int tid = threadIdx.x;
  const int lane = tid & 63;
  const int wv = tid >> 6;
  const int wm = wv & 1, wn = wv >> 1;
  const int z = blockIdx.z;
  const size_t m0 = (size_t)blockIdx.y * BM;
  const size_t n0 = (size_t)blockIdx.x * BN;

  const bf16_t* A16 = AF32 ? nullptr : ((const bf16_t*)Ap + (size_t)z * strA);
  const float*  A32 = AF32 ? ((const float*)Ap + (size_t)z * strA) : nullptr;
  const bf16_t* Bp  = Btp + (size_t)z * strB;

  f32x4 acc[MI][NI] = {};

  const int srow = tid >> 2;         // 0..63
  const int skc  = (tid & 3) * 8;    // 0,8,16,24

  for (int k0 = 0; k0 < Kdim; k0 += BK) {
    #pragma unroll
    for (int j = 0; j < BM / 64; ++j) {
      int r = j * 64 + srow;
      if (AF32) {
        const float* p = A32 + (m0 + r) * (size_t)lda + k0 + skc;
        f32x4 f0 = *(const f32x4*)p;
        f32x4 f1 = *(const f32x4*)(p + 4);
        short8 v;
        v[0] = bfbits(f0[0]); v[1] = bfbits(f0[1]); v[2] = bfbits(f0[2]); v[3] = bfbits(f0[3]);
        v[4] = bfbits(f1[0]); v[5] = bfbits(f1[1]); v[6] = bfbits(f1[2]); v[7] = bfbits(f1[3]);
        *(short8*)(&sA[r][skc]) = v;
      } else {
        *(short8*)(&sA[r][skc]) =
            *(const short8*)(A16 + (m0 + r) * (size_t)lda + k0 + skc);
      }
    }
    #pragma unroll
    for (int j = 0; j < BN / 64; ++j) {
      int r = j * 64 + srow;
      *(short8*)(&sB[r][skc]) =
          *(const short8*)(Bp + (n0 + r) * (size_t)ldb + k0 + skc);
    }
    __syncthreads();

    const int fm = wm * WTM + (lane & 15);
    const int fn = wn * WTN + (lane & 15);
    const int fk = (lane >> 4) * 8;
    short8 av[MI], bvv[NI];
    #pragma unroll
    for (int mi = 0; mi < MI; ++mi) av[mi] = *(const short8*)(&sA[fm + mi * 16][fk]);
    #pragma unroll
    for (int ni = 0; ni < NI; ++ni) bvv[ni] = *(const short8*)(&sB[fn + ni * 16][fk]);
    #pragma unroll
    for (int mi = 0; mi < MI; ++mi)
      #pragma unroll
      for (int ni = 0; ni < NI; ++ni)
        acc[mi][ni] = __builtin_amdgcn_mfma_f32_16x16x32_bf16(av[mi], bvv[ni],
                                                              acc[mi][ni], 0, 0, 0);
    __syncthreads();
  }

  const size_t cz = (size_t)z * strC;
  const int col0 = (int)n0 + wn * WTN + (lane & 15);
  const int row0 = (int)m0 + wm * WTM + ((lane >> 4) << 2);
  #pragma unroll
  for (int ni = 0; ni < NI; ++ni) {
    const int col = col0 + ni * 16;
    const float bval = BIAS ? bias[col] : 0.0f;
    #pragma unroll
    for (int mi = 0; mi < MI; ++mi) {
      #pragma unroll
      for (int r = 0; r < 4; ++r) {
        int row = row0 + mi * 16 + r;
        float v = acc[mi][ni][r];
        if (ALPHA) v *= alpha;
        v += bval;
        size_t off = cz + (size_t)row * ldc + col;
        if (RESID) v += resid[off];
        if (RELU) v = fmaxf(v, 0.0f);
        if (OUTF) Cf[off] = v;
        if (OUTB) Cb[off] = __float2bfloat16(v);
      }
    }
  }
}

// ---------------- fused attention: S=Q@K^T*0.125, softmax (exact, written to
// attn), ctx = P @ V. One block = 128 Q-rows of one head; 4 waves, each wave
// owns 32 rows (stats wave-local). S computed twice (stats pass + emit pass);
// P round-trips LDS as bf16 for the PV MFMA.
// Q,K: [64][1024][64] bf16 (stride 65536). Vt: [64][64][1024] bf16.
// attn: [64][1024][1024] fp32. ctx: [64][1024][64] bf16.
__global__ __launch_bounds__(256) void k_flash_attn(const bf16_t* __restrict__ Qb,
                                                    const bf16_t* __restrict__ Kb,
                                                    const bf16_t* __restrict__ Vt,
                                                    float* __restrict__ attn,
                                                    bf16_t* __restrict__ ctx) {
  constexpr int LP = 72;  // row pad: 144B rows, 16B aligned, 2-way-max conflicts (free)
  __shared__ __align__(16) bf16_t sQ[128][LP];
  __shared__ __align__(16) bf16_t sK[64][LP];
  __shared__ __align__(16) bf16_t sP[128][LP];
  __shared__ __align__(16) bf16_t sV[64][LP];

  const int tid = threadIdx.x;
  const int lane = tid & 63;
  const int wv = tid >> 6;            // wave owns rows wv*32 .. wv*32+31
  const int z = blockIdx.y;
  const int m0 = blockIdx.x * 128;

  const bf16_t* Qz = Qb + (size_t)z * 65536;
  const bf16_t* Kz = Kb + (size_t)z * 65536;
  const bf16_t* Vz = Vt + (size_t)z * 65536;
  float* az = attn + (size_t)z * 1048576;
  bf16_t* cz = ctx + (size_t)z * 65536;

  // stage Q tile [128][64]
  #pragma unroll
  for (int j = 0; j < 4; ++j) {
    int ii = j * 256 + tid;
    int r = ii >> 3, c = (ii & 7) * 8;
    *(short8*)(&sQ[r][c]) = *(const short8*)(Qz + (size_t)(m0 + r) * 64 + c);
  }
  __syncthreads();

  const int fr = lane & 15;           // frag row/col index
  const int fk = (lane >> 4) * 8;     // frag k offset
  const int crow = (lane >> 4) << 2;  // C/D row base

  // preload Q A-frags (sQ is read-only after this; K=64 -> 2 k-steps)
  short8 qf[2][2];
  #pragma unroll
  for (int mi = 0; mi < 2; ++mi)
    #pragma unroll
    for (int ks = 0; ks < 2; ++ks)
      qf[mi][ks] = *(const short8*)(&sQ[wv * 32 + mi * 16 + fr][ks * 32 + fk]);

  float m_run[2][4], s_run[2][4];
  #pragma unroll
  for (int mi = 0; mi < 2; ++mi)
    #pragma unroll
    for (int r = 0; r < 4; ++r) { m_run[mi][r] = -1e30f; s_run[mi][r] = 0.0f; }

  // ---- pass 1: online row max / sum-exp over all 16 K-chunks ----
  for (int c0 = 0; c0 < 1024; c0 += 64) {
    #pragma unroll
    for (int j = 0; j < 2; ++j) {
      int ii = j * 256 + tid;
      int r = ii >> 3, c = (ii & 7) * 8;
      *(short8*)(&sK[r][c]) = *(const short8*)(Kz + (size_t)(c0 + r) * 64 + c);
    }
    __syncthreads();
    f32x4 acc[2][4] = {};
    #pragma unroll
    for (int ks = 0; ks < 2; ++ks) {
      short8 bf[4];
      #pragma unroll
      for (int ni = 0; ni < 4; ++ni)
        bf[ni] = *(const short8*)(&sK[ni * 16 + fr][ks * 32 + fk]);
      #pragma unroll
      for (int mi = 0; mi < 2; ++mi)
        #pragma unroll
        for (int ni = 0; ni < 4; ++ni)
          acc[mi][ni] = __builtin_amdgcn_mfma_f32_16x16x32_bf16(qf[mi][ks], bf[ni],
                                                                acc[mi][ni], 0, 0, 0);
    }
    __syncthreads();  // all sK reads done before next stage
    #pragma unroll
    for (int mi = 0; mi < 2; ++mi)
      #pragma unroll
      for (int r = 0; r < 4; ++r) {
        float mx = fmaxf(fmaxf(acc[0][0][r], acc[0][0][r]), acc[mi][0][r]);
        mx = acc[mi][0][r];
        #pragma unroll
        for (int ni = 1; ni < 4; ++ni) mx = fmaxf(mx, acc[mi][ni][r]);
        mx *= 0.125f;
        #pragma unroll
        for (int o = 1; o < 16; o <<= 1) mx = fmaxf(mx, __shfl_xor(mx, o, 64));
        float mn = fmaxf(m_run[mi][r], mx);
        float se = 0.0f;
        #pragma unroll
        for (int ni = 0; ni < 4; ++ni) se += __expf(acc[mi][ni][r] * 0.125f - mn);
        #pragma unroll
        for (int o = 1; o < 16; o <<= 1) se += __shfl_xor(se, o, 64);
        s_run[mi][r] = s_run[mi][r] * __expf(m_run[mi][r] - mn) + se;
        m_run[mi][r] = mn;
      }
  }

  float inv_s[2][4];
  #pragma unroll
  for (int mi = 0; mi < 2; ++mi)
    #pragma unroll
    for (int r = 0; r < 4; ++r) inv_s[mi][r] = 1.0f / s_run[mi][r];

  // ---- pass 2: recompute S, emit exact softmax to attn, accumulate P@V ----
  f32x4 cacc[2][4] = {};
  for (int c0 = 0; c0 < 1024; c0 += 64) {
    #pragma unroll
    for (int j = 0; j < 2; ++j) {
      int ii = j * 256 + tid;
      int r = ii >> 3, c = (ii & 7) * 8;
      *(short8*)(&sK[r][c]) = *(const short8*)(Kz + (size_t)(c0 + r) * 64 + c);
      *(short8*)(&sV[r][c]) = *(const short8*)(Vz + (size_t)r * 1024 + c0 + c);
    }
    __syncthreads();
    f32x4 acc[2][4] = {};
    #pragma unroll
    for (int ks = 0; ks < 2; ++ks) {
      short8 bf[4];
      #pragma unroll
      for (int ni = 0; ni < 4; ++ni)
        bf[ni] = *(const short8*)(&sK[ni * 16 + fr][ks * 32 + fk]);
      #pragma unroll
      for (int mi = 0; mi < 2; ++mi)
        #pragma unroll
        for (int ni = 0; ni < 4; ++ni)
          acc[mi][ni] = __builtin_amdgcn_mfma_f32_16x16x32_bf16(qf[mi][ks], bf[ni],
                                                                acc[mi][ni], 0, 0, 0);
    }
    // normalized P: global write (mandatory output) + bf16 into LDS for PV
    #pragma unroll
    for (int mi = 0; mi < 2; ++mi)
      #pragma unroll
      for (int ni = 0; ni < 4; ++ni)
        #pragma unroll
        for (int r = 0; r < 4; ++r) {
          int row = wv * 32 + mi * 16 + crow + r;
          float p = __expf(acc[mi][ni][r] * 0.125f - m_run[mi][r]) * inv_s[mi][r];
          az[(size_t)(m0 + row) * 1024 + c0 + ni * 16 + fr] = p;
          sP[row][ni * 16 + fr] = __float2bfloat16(p);
        }
    __syncthreads();  // sP visible to all waves
    #pragma unroll
    for (int ks = 0; ks < 2; ++ks) {
      short8 pa[2], vb[4];
      #pragma unroll
      for (int mi = 0; mi < 2; ++mi)
        pa[mi] = *(const short8*)(&sP[wv * 32 + mi * 16 + fr][ks * 32 + fk]);
      #pragma unroll
      for (int ni = 0; ni < 4; ++ni)
        vb[ni] = *(const short8*)(&sV[ni * 16 + fr][ks * 32 + fk]);
      #pragma unroll
      for (int mi = 0; mi < 2; ++mi)
        #pragma unroll
        for (int ni = 0; ni < 4; ++ni)
          cacc[mi][ni] = __builtin_amdgcn_mfma_f32_16x16x32_bf16(pa[mi], vb[ni],
                                                                 cacc[mi][ni], 0, 0, 0);
    }
    __syncthreads();  // all sK/sV/sP reads done before next stage
  }

  // ctx write: [1024][64] bf16 per head
  #pragma unroll
  for (int mi = 0; mi < 2; ++mi)
    #pragma unroll
    for (int ni = 0; ni < 4; ++ni)
      #pragma unroll
      for (int r = 0; r < 4; ++r) {
        int row = wv * 32 + mi * 16 + crow + r;
        cz[(size_t)(m0 + row) * 64 + ni * 16 + fr] = __float2bfloat16(cacc[mi][ni][r]);
      }
}

// ---------------- row layernorm, width 1024, in place (+optional bf16 copy) -------
__global__ __launch_bounds__(256) void k_layernorm(float* __restrict__ io,
                                                   bf16_t* __restrict__ ob,
                                                   const float* __restrict__ g,
                                                   const float* __restrict__ bta) {
  float* r = io + (size_t)blockIdx.x * 1024;
  const int t = threadIdx.x;
  f32x4 x = *(const f32x4*)(r + t * 4);
  float s = x[0] + x[1] + x[2] + x[3];
  float s2 = x[0] * x[0] + x[1] * x[1] + x[2] * x[2] + x[3] * x[3];
  #pragma unroll
  for (int o = 32; o > 0; o >>= 1) { s += __shfl_xor(s, o, 64); s2 += __shfl_xor(s2, o, 64); }
  __shared__ float as[4], as2[4];
  if ((t & 63) == 0) { as[t >> 6] = s; as2[t >> 6] = s2; }
  __syncthreads();
  s = as[0] + as[1] + as[2] + as[3];
  s2 = as2[0] + as2[1] + as2[2] + as2[3];
  float mu = s * (1.0f / 1024.0f);
  float var = s2 * (1.0f / 1024.0f) - mu * mu;
  float rs = rsqrtf(var + 1e-5f);
  f32x4 gg = *(const f32x4*)(g + t * 4);
  f32x4 bb = *(const f32x4*)(bta + t * 4);
  f32x4 y;
  #pragma unroll
  for (int i = 0; i < 4; ++i) y[i] = (x[i] - mu) * rs * gg[i] + bb[i];
  *(f32x4*)(r + t * 4) = y;
  if (ob) {
    short4v o4;
    o4[0] = bfbits(y[0]); o4[1] = bfbits(y[1]); o4[2] = bfbits(y[2]); o4[3] = bfbits(y[3]);
    *(short4v*)((short*)ob + (size_t)blockIdx.x * 1024 + t * 4) = o4;
  }
}

extern "C" void kernel_launch(void* const* d_in, const int* in_sizes, int n_in,
                              void* d_out, int out_size, void* d_ws, size_t ws_size,
                              hipStream_t stream) {
  (void)in_sizes; (void)n_in; (void)out_size;
  const float* inputs = (const float*)d_in[0];
  const float* Wq = (const float*)d_in[1];  const float* bq = (const float*)d_in[2];
  const float* Wk = (const float*)d_in[3];  const float* bk = (const float*)d_in[4];
  const float* Wv = (const float*)d_in[5];  const float* bv = (const float*)d_in[6];
  const float* Wo = (const float*)d_in[7];  const float* bo = (const float*)d_in[8];
  const float* ln1g = (const float*)d_in[9];  const float* ln1b = (const float*)d_in[10];
  const float* W1 = (const float*)d_in[11]; const float* b1 = (const float*)d_in[12];
  const float* W2 = (const float*)d_in[13]; const float* b2 = (const float*)d_in[14];
  const float* ln2g = (const float*)d_in[15]; const float* ln2b = (const float*)d_in[16];

  const size_t MB = 1ull << 20;
  if (ws_size < 96 * MB) return;  // layout below needs 96 MB scratch

  char* ws = (char*)d_ws;
  bf16_t* WQT  = (bf16_t*)(ws + 0 * MB);   // [1024][1024]
  bf16_t* WKT  = (bf16_t*)(ws + 2 * MB);
  bf16_t* WVT  = (bf16_t*)(ws + 4 * MB);
  bf16_t* WOT  = (bf16_t*)(ws + 6 * MB);
  bf16_t* W1T  = (bf16_t*)(ws + 8 * MB);   // [4096][1024]
  bf16_t* W2T  = (bf16_t*)(ws + 16 * MB);  // [1024][4096]
  bf16_t* XB   = (bf16_t*)(ws + 24 * MB);  // [4096][1024]; dead after QKV
  bf16_t* QB   = (bf16_t*)(ws + 32 * MB);  // dead after flash
  bf16_t* KB   = (bf16_t*)(ws + 40 * MB);  // dead after flash
  bf16_t* VB   = (bf16_t*)(ws + 48 * MB);  // dead after Vt transpose
  bf16_t* VT   = (bf16_t*)(ws + 56 * MB);  // [64 batches][64][1024]; dead after flash
  bf16_t* CTX  = (bf16_t*)(ws + 24 * MB);  // reuse XB slot
  float*  OUT1F = (float*)(ws + 40 * MB);  // fp32 [4096][1024] (reuse KB+VB slots)
  bf16_t* OUT1B = (bf16_t*)(ws + 32 * MB); // reuse QB slot
  bf16_t* HB   = (bf16_t*)(ws + 64 * MB);  // [4096][4096]

  float* outF = (float*)d_out;             // [4096][1024]
  float* attn = outF + 4194304;            // [64][1024][1024] fp32 (final output region)

  // --- prep: bf16 input copy + transposed bf16 weights ---
  k_f32_to_bf16<<<4096, 256, 0, stream>>>(inputs, XB);
  k_transpose_f32_bf16<<<dim3(32, 32), 256, 0, stream>>>(Wq, WQT, 1024, 1024);
  k_transpose_f32_bf16<<<dim3(32, 32), 256, 0, stream>>>(Wk, WKT, 1024, 1024);
  k_transpose_f32_bf16<<<dim3(32, 32), 256, 0, stream>>>(Wv, WVT, 1024, 1024);
  k_transpose_f32_bf16<<<dim3(32, 32), 256, 0, stream>>>(Wo, WOT, 1024, 1024);
  k_transpose_f32_bf16<<<dim3(128, 32), 256, 0, stream>>>(W1, W1T, 1024, 4096);
  k_transpose_f32_bf16<<<dim3(32, 128), 256, 0, stream>>>(W2, W2T, 4096, 1024);

  // --- QKV projections: [4096,1024] @ [1024,1024] ---
  k_gemm_bt<128, 128, false, false, true, false, false, false, true>
      <<<dim3(8, 32, 1), 256, 0, stream>>>(XB, WQT, nullptr, QB, bq, nullptr,
                                           1024, 1024, 1024, 1024, 1.0f, 0, 0, 0);
  k_gemm_bt<128, 128, false, false, true, false, false, false, true>
      <<<dim3(8, 32, 1), 256, 0, stream>>>(XB, WKT, nullptr, KB, bk, nullptr,
                                           1024, 1024, 1024, 1024, 1.0f, 0, 0, 0);
  k_gemm_bt<128, 128, false, false, true, false, false, false, true>
      <<<dim3(8, 32, 1), 256, 0, stream>>>(XB, WVT, nullptr, VB, bv, nullptr,
                                           1024, 1024, 1024, 1024, 1.0f, 0, 0, 0);

  // --- per-"head" V transpose: [1024][64] -> [64][1024], 64 batches ---
  k_transpose_bf16_b<<<dim3(2, 32, 64), 256, 0, stream>>>(VB, VT, 1024, 64, 65536, 65536);

  // --- fused scores+softmax+PV; writes exact attn fp32 + ctx bf16 ---
  k_flash_attn<<<dim3(8, 64), 256, 0, stream>>>(QB, KB, VT, attn, CTX);

  // --- out-proj + bias + residual(inputs) -> OUT1F fp32 ---
  k_gemm_bt<128, 128, false, false, true, false, true, true, false>
      <<<dim3(8, 32, 1), 256, 0, stream>>>(CTX, WOT, OUT1F, nullptr, bo, inputs,
                                           1024, 1024, 1024, 1024, 1.0f, 0, 0, 0);

  // --- LN1 in place + bf16 copy ---
  k_layernorm<<<4096, 256, 0, stream>>>(OUT1F, OUT1B, ln1g, ln1b);

  // --- FFN1: relu(out1 @ W1 + b1) -> HB bf16 [4096][4096] ---
  k_gemm_bt<128, 128, false, false, true, true, false, false, true>
      <<<dim3(32, 32, 1), 256, 0, stream>>>(OUT1B, W1T, nullptr, HB, b1, nullptr,
                                            1024, 1024, 1024, 4096, 1.0f, 0, 0, 0);

  // --- FFN2: HB @ W2 + b2 + out1 -> d_out[0:4M] fp32 ---
  k_gemm_bt<128, 128, false, false, true, false, true, true, false>
      <<<dim3(8, 32, 1), 256, 0, stream>>>(HB, W2T, outF, nullptr, b2, OUT1F,
                                           4096, 4096, 4096, 1024, 1.0f, 0, 0, 0);

  // --- LN2 in place on d_out ---
  k_layernorm<<<4096, 256, 0, stream>>>(outF, nullptr, ln2g, ln2b);
}

// Round 2
// 707.656 us; speedup vs baseline: 1.0770x; 1.0770x over previous
//
#include <hip/hip_runtime.h>
#include <hip/hip_bf16.h>
#include <stdint.h>

// EncoderLayer on MI355X: bf16 MFMA GEMMs + fp32 softmax/LN epilogues.
// Pipeline: prep(convert/transpose) -> fused QKV -> Vt -> flash(scores+softmax+PV,
//           writes exact attn) -> Wo+resid -> LN1 -> FFN1(relu) -> FFN2+resid -> LN2.
// GEMM staging uses global_load_lds width=16 (m97 structure, ~874 TF documented).

using bf16_t  = __hip_bfloat16;
using short8  = __attribute__((ext_vector_type(8))) short;
using short4v = __attribute__((ext_vector_type(4))) short;
using f32x4   = __attribute__((ext_vector_type(4))) float;

#define DEV static __device__ __forceinline__

DEV short bfbits(float f) {
  bf16_t h = __float2bfloat16(f);
  union { bf16_t h; short s; } u; u.h = h; return u.s;
}

// async global->LDS, 16 bytes per lane; lds must be wave-uniform, HW writes
// lds + lane*16 (cdna_hip_programming.md §5: width=16 = 874 TF lever).
DEV void gload_lds16(const bf16_t* g, bf16_t* lds) {
  __builtin_amdgcn_global_load_lds(
      (const __attribute__((address_space(1))) void*)g,
      (__attribute__((address_space(3))) void*)lds, 16, 0, 0);
}

// ---------------- elementwise fp32 -> bf16 (4 elems/thread) ----------------
__global__ __launch_bounds__(256) void k_f32_to_bf16(const float* __restrict__ in,
                                                     bf16_t* __restrict__ out) {
  size_t i = ((size_t)blockIdx.x * 256 + threadIdx.x) * 4;
  f32x4 x = *(const f32x4*)(in + i);
  short4v o;
  o[0] = bfbits(x[0]); o[1] = bfbits(x[1]); o[2] = bfbits(x[2]); o[3] = bfbits(x[3]);
  *(short4v*)((short*)out + i) = o;
}

// ---------------- transpose fp32 [R][C] -> bf16 [C][R] ----------------
__global__ __launch_bounds__(256) void k_transpose_f32_bf16(const float* __restrict__ in,
                                                            bf16_t* __restrict__ out,
                                                            int R, int C) {
  __shared__ float tile[32][33];
  int tx = threadIdx.x & 31, ty = threadIdx.x >> 5;   // 32 x 8
  int r0 = blockIdx.y * 32, c0 = blockIdx.x * 32;
  #pragma unroll
  for (int i = 0; i < 4; ++i)
    tile[ty + i * 8][tx] = in[(size_t)(r0 + ty + i * 8) * C + c0 + tx];
  __syncthreads();
  #pragma unroll
  for (int i = 0; i < 4; ++i)
    out[(size_t)(c0 + ty + i * 8) * R + r0 + tx] = __float2bfloat16(tile[tx][ty + i * 8]);
}

// ---------------- batched transpose bf16 [R][C] -> [C][R] ----------------
__global__ __launch_bounds__(256) void k_transpose_bf16_b(const bf16_t* __restrict__ in,
                                                          bf16_t* __restrict__ out,
                                                          int R, int C, long sIn, long sOut) {
  __shared__ bf16_t tile[32][33];
  const bf16_t* inz = in + (size_t)blockIdx.z * sIn;
  bf16_t* outz = out + (size_t)blockIdx.z * sOut;
  int tx = threadIdx.x & 31, ty = threadIdx.x >> 5;
  int r0 = blockIdx.y * 32, c0 = blockIdx.x * 32;
  #pragma unroll
  for (int i = 0; i < 4; ++i)
    tile[ty + i * 8][tx] = inz[(size_t)(r0 + ty + i * 8) * C + c0 + tx];
  __syncthreads();
  #pragma unroll
  for (int i = 0; i < 4; ++i)
    outz[(size_t)(c0 + ty + i * 8) * R + r0 + tx] = tile[tx][ty + i * 8];
}

// ---------------- GEMM: C[M][N] = A[M][K](bf16) @ Bt[N][K](bf16) ----------------
// m97 structure: block 256 thr = 4 waves (2x2), wave tile 64x64, MFMA 16x16x32,
// BK=32, LINEAR LDS [128][32] (64B rows) staged via global_load_lds width 16.
// A-frag: A[m=lane&15][k=(lane>>4)*8+j]; C/D: col=lane&15, row=(lane>>4)*4+reg.
// QKV3: Bt is 3 vertically-concatenated [1024][K] weights; output routed to
// Cb + (n0>>10)*4194304 with per-tensor bias.
template<int BM, int BN, bool ALPHA, bool BIAS, bool RELU, bool RESID,
         bool OUTF, bool OUTB, bool QKV3>
__global__ __launch_bounds__(256)
void k_gemm_bt(const bf16_t* __restrict__ A, const bf16_t* __restrict__ Bt,
               float* __restrict__ Cf, bf16_t* __restrict__ Cb,
               const float* __restrict__ bias, const float* __restrict__ bias2,
               const float* __restrict__ bias3, const float* __restrict__ resid,
               int Kdim, int lda, int ldb, int ldc, float alpha) {
  constexpr int BK = 32;
  constexpr int WTM = BM / 2, WTN = BN / 2;
  constexpr int MI = WTM / 16, NI = WTN / 16;
  __shared__ __align__(16) bf16_t sA[BM * BK];
  __shared__ __align__(16) bf16_t sB[BN * BK];

  const int tid = threadIdx.x;
  const int lane = tid & 63;
  const int wv = tid >> 6;
  const int wm = wv & 1, wn = wv >> 1;
  const size_t m0 = (size_t)blockIdx.y * BM;
  const size_t n0 = (size_t)blockIdx.x * BN;

  f32x4 acc[MI][NI] = {};

  // staging geometry: chunk = 16 rows = 1KB; lane l covers (row l>>2, 16B col l&3)
  const int rr = lane >> 2, cc = (lane & 3) * 8;
  const bf16_t* Arow = A + (m0 + rr) * (size_t)lda + cc;   // + chunk*16*lda + k0
  const bf16_t* Brow = Bt + (n0 + rr) * (size_t)ldb + cc;

  const int fm = wm * WTM + (lane & 15);
  const int fn = wn * WTN + (lane & 15);
  const int fk = (lane >> 4) * 8;

  for (int k0 = 0; k0 < Kdim; k0 += BK) {
    #pragma unroll
    for (int j = 0; j < BM / 64; ++j) {
      int c = j * 4 + wv;                       // chunk id 0..BM/16-1, wave-uniform
      gload_lds16(Arow + (size_t)c * 16 * lda + k0, sA + c * 512);
    }
    #pragma unroll
    for (int j = 0; j < BN / 64; ++j) {
      int c = j * 4 + wv;
      gload_lds16(Brow + (size_t)c * 16 * ldb + k0, sB + c * 512);
    }
    __syncthreads();   // drains vmcnt: LDS tiles complete

    short8 av[MI], bvv[NI];
    #pragma unroll
    for (int mi = 0; mi < MI; ++mi) av[mi] = *(const short8*)(sA + (fm + mi * 16) * BK + fk);
    #pragma unroll
    for (int ni = 0; ni < NI; ++ni) bvv[ni] = *(const short8*)(sB + (fn + ni * 16) * BK + fk);
    #pragma unroll
    for (int mi = 0; mi < MI; ++mi)
      #pragma unroll
      for (int ni = 0; ni < NI; ++ni)
        acc[mi][ni] = __builtin_amdgcn_mfma_f32_16x16x32_bf16(av[mi], bvv[ni],
                                                              acc[mi][ni], 0, 0, 0);
    __syncthreads();
  }

  // epilogue
  const int tz = QKV3 ? (int)(n0 >> 10) : 0;                    // uniform per block
  const float* bp = BIAS ? (QKV3 ? (tz == 0 ? bias : (tz == 1 ? bias2 : bias3))
                                 : bias) : nullptr;
  bf16_t* cb = QKV3 ? (Cb + (size_t)tz * 4194304) : Cb;
  const int col0 = (int)n0 + wn * WTN + (lane & 15);
  const int row0 = (int)m0 + wm * WTM + ((lane >> 4) << 2);
  #pragma unroll
  for (int ni = 0; ni < NI; ++ni) {
    const int col = col0 + ni * 16;
    const int colw = QKV3 ? (col & 1023) : col;
    const float bval = BIAS ? bp[colw] : 0.0f;
    #pragma unroll
    for (int mi = 0; mi < MI; ++mi) {
      #pragma unroll
      for (int r = 0; r < 4; ++r) {
        int row = row0 + mi * 16 + r;
        float v = acc[mi][ni][r];
        if (ALPHA) v *= alpha;
        v += bval;
        size_t off = (size_t)row * ldc + colw;
        if (RESID) v += resid[off];
        if (RELU) v = fmaxf(v, 0.0f);
        if (OUTF) Cf[off] = v;
        if (OUTB) cb[off] = __float2bfloat16(v);
      }
    }
  }
}

// ---------------- fused attention: S=Q@K^T*0.125, softmax (exact, written to
// attn), ctx = P @ V. One block = 128 Q-rows of one head; 4 waves, each wave
// owns 32 rows (stats wave-local). S computed twice (stats pass + emit pass);
// P round-trips LDS as bf16 for the PV MFMA.
// Q,K: [64][1024][64] bf16 (stride 65536). Vt: [64][64][1024] bf16.
// attn: [64][1024][1024] fp32. ctx: [64][1024][64] bf16.
__global__ __launch_bounds__(256) void k_flash_attn(const bf16_t* __restrict__ Qb,
                                                    const bf16_t* __restrict__ Kb,
                                                    const bf16_t* __restrict__ Vt,
                                                    float* __restrict__ attn,
                                                    bf16_t* __restrict__ ctx) {
  constexpr int LP = 72;  // row pad: 144B rows, 16B aligned, 2-way-max conflicts (free)
  __shared__ __align__(16) bf16_t sQ[128][LP];
  __shared__ __align__(16) bf16_t sK[64][LP];
  __shared__ __align__(16) bf16_t sP[128][LP];
  __shared__ __align__(16) bf16_t sV[64][LP];

  const int tid = threadIdx.x;
  const int lane = tid & 63;
  const int wv = tid >> 6;            // wave owns rows wv*32 .. wv*32+31
  const int z = blockIdx.y;
  const int m0 = blockIdx.x * 128;

  const bf16_t* Qz = Qb + (size_t)z * 65536;
  const bf16_t* Kz = Kb + (size_t)z * 65536;
  const bf16_t* Vz = Vt + (size_t)z * 65536;
  float* az = attn + (size_t)z * 1048576;
  bf16_t* cz = ctx + (size_t)z * 65536;

  // stage Q tile [128][64]
  #pragma unroll
  for (int j = 0; j < 4; ++j) {
    int ii = j * 256 + tid;
    int r = ii >> 3, c = (ii & 7) * 8;
    *(short8*)(&sQ[r][c]) = *(const short8*)(Qz + (size_t)(m0 + r) * 64 + c);
  }
  __syncthreads();

  const int fr = lane & 15;           // frag row/col index
  const int fk = (lane >> 4) * 8;     // frag k offset
  const int crow = (lane >> 4) << 2;  // C/D row base

  // preload Q A-frags (sQ is read-only after this; K=64 -> 2 k-steps)
  short8 qf[2][2];
  #pragma unroll
  for (int mi = 0; mi < 2; ++mi)
    #pragma unroll
    for (int ks = 0; ks < 2; ++ks)
      qf[mi][ks] = *(const short8*)(&sQ[wv * 32 + mi * 16 + fr][ks * 32 + fk]);

  float m_run[2][4], s_run[2][4];
  #pragma unroll
  for (int mi = 0; mi < 2; ++mi)
    #pragma unroll
    for (int r = 0; r < 4; ++r) { m_run[mi][r] = -1e30f; s_run[mi][r] = 0.0f; }

  // ---- pass 1: online row max / sum-exp over all 16 K-chunks ----
  for (int c0 = 0; c0 < 1024; c0 += 64) {
    #pragma unroll
    for (int j = 0; j < 2; ++j) {
      int ii = j * 256 + tid;
      int r = ii >> 3, c = (ii & 7) * 8;
      *(short8*)(&sK[r][c]) = *(const short8*)(Kz + (size_t)(c0 + r) * 64 + c);
    }
    __syncthreads();
    f32x4 acc[2][4] = {};
    #pragma unroll
    for (int ks = 0; ks < 2; ++ks) {
      short8 bf[4];
      #pragma unroll
      for (int ni = 0; ni < 4; ++ni)
        bf[ni] = *(const short8*)(&sK[ni * 16 + fr][ks * 32 + fk]);
      #pragma unroll
      for (int mi = 0; mi < 2; ++mi)
        #pragma unroll
        for (int ni = 0; ni < 4; ++ni)
          acc[mi][ni] = __builtin_amdgcn_mfma_f32_16x16x32_bf16(qf[mi][ks], bf[ni],
                                                                acc[mi][ni], 0, 0, 0);
    }
    __syncthreads();  // all sK reads done before next stage
    #pragma unroll
    for (int mi = 0; mi < 2; ++mi)
      #pragma unroll
      for (int r = 0; r < 4; ++r) {
        float mx = acc[mi][0][r];
        #pragma unroll
        for (int ni = 1; ni < 4; ++ni) mx = fmaxf(mx, acc[mi][ni][r]);
        mx *= 0.125f;
        #pragma unroll
        for (int o = 1; o < 16; o <<= 1) mx = fmaxf(mx, __shfl_xor(mx, o, 64));
        float mn = fmaxf(m_run[mi][r], mx);
        float se = 0.0f;
        #pragma unroll
        for (int ni = 0; ni < 4; ++ni) se += __expf(acc[mi][ni][r] * 0.125f - mn);
        #pragma unroll
        for (int o = 1; o < 16; o <<= 1) se += __shfl_xor(se, o, 64);
        s_run[mi][r] = s_run[mi][r] * __expf(m_run[mi][r] - mn) + se;
        m_run[mi][r] = mn;
      }
  }

  float inv_s[2][4];
  #pragma unroll
  for (int mi = 0; mi < 2; ++mi)
    #pragma unroll
    for (int r = 0; r < 4; ++r) inv_s[mi][r] = 1.0f / s_run[mi][r];

  // ---- pass 2: recompute S, emit exact softmax to attn, accumulate P@V ----
  f32x4 cacc[2][4] = {};
  for (int c0 = 0; c0 < 1024; c0 += 64) {
    #pragma unroll
    for (int j = 0; j < 2; ++j) {
      int ii = j * 256 + tid;
      int r = ii >> 3, c = (ii & 7) * 8;
      *(short8*)(&sK[r][c]) = *(const short8*)(Kz + (size_t)(c0 + r) * 64 + c);
      *(short8*)(&sV[r][c]) = *(const short8*)(Vz + (size_t)r * 1024 + c0 + c);
    }
    __syncthreads();
    f32x4 acc[2][4] = {};
    #pragma unroll
    for (int ks = 0; ks < 2; ++ks) {
      short8 bf[4];
      #pragma unroll
      for (int ni = 0; ni < 4; ++ni)
        bf[ni] = *(const short8*)(&sK[ni * 16 + fr][ks * 32 + fk]);
      #pragma unroll
      for (int mi = 0; mi < 2; ++mi)
        #pragma unroll
        for (int ni = 0; ni < 4; ++ni)
          acc[mi][ni] = __builtin_amdgcn_mfma_f32_16x16x32_bf16(qf[mi][ks], bf[ni],
                                                                acc[mi][ni], 0, 0, 0);
    }
    // normalized P: global write (mandatory output) + bf16 into LDS for PV
    #pragma unroll
    for (int mi = 0; mi < 2; ++mi)
      #pragma unroll
      for (int ni = 0; ni < 4; ++ni)
        #pragma unroll
        for (int r = 0; r < 4; ++r) {
          int row = wv * 32 + mi * 16 + crow + r;
          float p = __expf(acc[mi][ni][r] * 0.125f - m_run[mi][r]) * inv_s[mi][r];
          az[(size_t)(m0 + row) * 1024 + c0 + ni * 16 + fr] = p;
          sP[row][ni * 16 + fr] = __float2bfloat16(p);
        }
    __syncthreads();  // sP visible to all waves
    #pragma unroll
    for (int ks = 0; ks < 2; ++ks) {
      short8 pa[2], vb[4];
      #pragma unroll
      for (int mi = 0; mi < 2; ++mi)
        pa[mi] = *(const short8*)(&sP[wv * 32 + mi * 16 + fr][ks * 32 + fk]);
      #pragma unroll
      for (int ni = 0; ni < 4; ++ni)
        vb[ni] = *(const short8*)(&sV[ni * 16 + fr][ks * 32 + fk]);
      #pragma unroll
      for (int mi = 0; mi < 2; ++mi)
        #pragma unroll
        for (int ni = 0; ni < 4; ++ni)
          cacc[mi][ni] = __builtin_amdgcn_mfma_f32_16x16x32_bf16(pa[mi], vb[ni],
                                                                 cacc[mi][ni], 0, 0, 0);
    }
    __syncthreads();  // all sK/sV/sP reads done before next stage
  }

  // ctx write: [1024][64] bf16 per head
  #pragma unroll
  for (int mi = 0; mi < 2; ++mi)
    #pragma unroll
    for (int ni = 0; ni < 4; ++ni)
      #pragma unroll
      for (int r = 0; r < 4; ++r) {
        int row = wv * 32 + mi * 16 + crow + r;
        cz[(size_t)(m0 + row) * 64 + ni * 16 + fr] = __float2bfloat16(cacc[mi][ni][r]);
      }
}

// ---------------- row layernorm, width 1024, in place (+optional bf16 copy) -------
__global__ __launch_bounds__(256) void k_layernorm(float* __restrict__ io,
                                                   bf16_t* __restrict__ ob,
                                                   const float* __restrict__ g,
                                                   const float* __restrict__ bta) {
  float* r = io + (size_t)blockIdx.x * 1024;
  const int t = threadIdx.x;
  f32x4 x = *(const f32x4*)(r + t * 4);
  float s = x[0] + x[1] + x[2] + x[3];
  float s2 = x[0] * x[0] + x[1] * x[1] + x[2] * x[2] + x[3] * x[3];
  #pragma unroll
  for (int o = 32; o > 0; o >>= 1) { s += __shfl_xor(s, o, 64); s2 += __shfl_xor(s2, o, 64); }
  __shared__ float as[4], as2[4];
  if ((t & 63) == 0) { as[t >> 6] = s; as2[t >> 6] = s2; }
  __syncthreads();
  s = as[0] + as[1] + as[2] + as[3];
  s2 = as2[0] + as2[1] + as2[2] + as2[3];
  float mu = s * (1.0f / 1024.0f);
  float var = s2 * (1.0f / 1024.0f) - mu * mu;
  float rs = rsqrtf(var + 1e-5f);
  f32x4 gg = *(const f32x4*)(g + t * 4);
  f32x4 bb = *(const f32x4*)(bta + t * 4);
  f32x4 y;
  #pragma unroll
  for (int i = 0; i < 4; ++i) y[i] = (x[i] - mu) * rs * gg[i] + bb[i];
  *(f32x4*)(r + t * 4) = y;
  if (ob) {
    short4v o4;
    o4[0] = bfbits(y[0]); o4[1] = bfbits(y[1]); o4[2] = bfbits(y[2]); o4[3] = bfbits(y[3]);
    *(short4v*)((short*)ob + (size_t)blockIdx.x * 1024 + t * 4) = o4;
  }
}

extern "C" void kernel_launch(void* const* d_in, const int* in_sizes, int n_in,
                              void* d_out, int out_size, void* d_ws, size_t ws_size,
                              hipStream_t stream) {
  (void)in_sizes; (void)n_in; (void)out_size;
  const float* inputs = (const float*)d_in[0];
  const float* Wq = (const float*)d_in[1];  const float* bq = (const float*)d_in[2];
  const float* Wk = (const float*)d_in[3];  const float* bk = (const float*)d_in[4];
  const float* Wv = (const float*)d_in[5];  const float* bv = (const float*)d_in[6];
  const float* Wo = (const float*)d_in[7];  const float* bo = (const float*)d_in[8];
  const float* ln1g = (const float*)d_in[9];  const float* ln1b = (const float*)d_in[10];
  const float* W1 = (const float*)d_in[11]; const float* b1 = (const float*)d_in[12];
  const float* W2 = (const float*)d_in[13]; const float* b2 = (const float*)d_in[14];
  const float* ln2g = (const float*)d_in[15]; const float* ln2b = (const float*)d_in[16];

  const size_t MB = 1ull << 20;
  if (ws_size < 96 * MB) return;  // layout below needs 96 MB scratch

  char* ws = (char*)d_ws;
  bf16_t* WQT  = (bf16_t*)(ws + 0 * MB);   // [1024][1024]; WQT/WKT/WVT contiguous
  bf16_t* WKT  = (bf16_t*)(ws + 2 * MB);   //   -> fused QKV sees [3072][1024]
  bf16_t* WVT  = (bf16_t*)(ws + 4 * MB);
  bf16_t* WOT  = (bf16_t*)(ws + 6 * MB);
  bf16_t* W1T  = (bf16_t*)(ws + 8 * MB);   // [4096][1024]
  bf16_t* W2T  = (bf16_t*)(ws + 16 * MB);  // [1024][4096]
  bf16_t* XB   = (bf16_t*)(ws + 24 * MB);  // [4096][1024]; dead after QKV
  bf16_t* QB   = (bf16_t*)(ws + 32 * MB);  // QB/KB/VB contiguous, 8MB stride
  bf16_t* VB   = (bf16_t*)(ws + 48 * MB);  // dead after Vt transpose
  bf16_t* VT   = (bf16_t*)(ws + 56 * MB);  // [64 batches][64][1024]; dead after flash
  bf16_t* KB   = (bf16_t*)(ws + 40 * MB);
  bf16_t* CTX  = (bf16_t*)(ws + 24 * MB);  // reuse XB slot
  float*  OUT1F = (float*)(ws + 40 * MB);  // fp32 [4096][1024] (reuse KB+VB slots)
  bf16_t* OUT1B = (bf16_t*)(ws + 32 * MB); // reuse QB slot
  bf16_t* HB   = (bf16_t*)(ws + 64 * MB);  // [4096][4096]

  float* outF = (float*)d_out;             // [4096][1024]
  float* attn = outF + 4194304;            // [64][1024][1024] fp32 (final output region)

  // --- prep: bf16 input copy + transposed bf16 weights ---
  k_f32_to_bf16<<<4096, 256, 0, stream>>>(inputs, XB);
  k_transpose_f32_bf16<<<dim3(32, 32), 256, 0, stream>>>(Wq, WQT, 1024, 1024);
  k_transpose_f32_bf16<<<dim3(32, 32), 256, 0, stream>>>(Wk, WKT, 1024, 1024);
  k_transpose_f32_bf16<<<dim3(32, 32), 256, 0, stream>>>(Wv, WVT, 1024, 1024);
  k_transpose_f32_bf16<<<dim3(32, 32), 256, 0, stream>>>(Wo, WOT, 1024, 1024);
  k_transpose_f32_bf16<<<dim3(128, 32), 256, 0, stream>>>(W1, W1T, 1024, 4096);
  k_transpose_f32_bf16<<<dim3(32, 128), 256, 0, stream>>>(W2, W2T, 4096, 1024);

  // --- fused QKV: [4096,1024] @ [1024,3072] -> QB/KB/VB (routed by n-block) ---
  k_gemm_bt<128, 128, false, true, false, false, false, true, true>
      <<<dim3(24, 32), 256, 0, stream>>>(XB, WQT, nullptr, QB, bq, bk, bv, nullptr,
                                         1024, 1024, 1024, 1024, 1.0f);

  // --- per-"head" V transpose: [1024][64] -> [64][1024], 64 batches ---
  k_transpose_bf16_b<<<dim3(2, 32, 64), 256, 0, stream>>>(VB, VT, 1024, 64, 65536, 65536);

  // --- fused scores+softmax+PV; writes exact attn fp32 + ctx bf16 ---
  k_flash_attn<<<dim3(8, 64), 256, 0, stream>>>(QB, KB, VT, attn, CTX);

  // --- out-proj + bias + residual(inputs) -> OUT1F fp32 ---
  k_gemm_bt<128, 128, false, true, false, true, true, false, false>
      <<<dim3(8, 32), 256, 0, stream>>>(CTX, WOT, OUT1F, nullptr, bo, nullptr, nullptr,
                                        inputs, 1024, 1024, 1024, 1024, 1.0f);

  // --- LN1 in place + bf16 copy ---
  k_layernorm<<<4096, 256, 0, stream>>>(OUT1F, OUT1B, ln1g, ln1b);

  // --- FFN1: relu(out1 @ W1 + b1) -> HB bf16 [4096][4096] ---
  k_gemm_bt<128, 128, false, true, true, false, false, true, false>
      <<<dim3(32, 32), 256, 0, stream>>>(OUT1B, W1T, nullptr, HB, b1, nullptr, nullptr,
                                         nullptr, 1024, 1024, 1024, 4096, 1.0f);

  // --- FFN2: HB @ W2 + b2 + out1 -> d_out[0:4M] fp32 ---
  k_gemm_bt<128, 128, false, true, false, true, true, false, false>
      <<<dim3(8, 32), 256, 0, stream>>>(HB, W2T, outF, nullptr, b2, nullptr, nullptr,
                                        OUT1F, 4096, 4096, 4096, 1024, 1.0f);

  // --- LN2 in place on d_out ---
  k_layernorm<<<4096, 256, 0, stream>>>(outF, nullptr, ln2g, ln2b);
}

// Round 3
// 694.075 us; speedup vs baseline: 1.0981x; 1.0196x over previous
//
#include <hip/hip_runtime.h>
#include <hip/hip_bf16.h>
#include <stdint.h>

// EncoderLayer on MI355X: bf16 MFMA GEMMs + fp32 softmax/LN epilogues.
// Pipeline: prep(convert/transpose) -> fused QKV (Q pre-scaled 1/8) -> Vt ->
//           flash(scores+softmax+PV, writes exact attn; T14 async-stage + dbuf)
//           -> Wo+resid -> LN1 -> FFN1(relu) -> FFN2+resid -> LN2.
// GEMM staging uses global_load_lds width=16 (m97 structure).

using bf16_t  = __hip_bfloat16;
using short8  = __attribute__((ext_vector_type(8))) short;
using short4v = __attribute__((ext_vector_type(4))) short;
using f32x4   = __attribute__((ext_vector_type(4))) float;

#define DEV static __device__ __forceinline__

DEV short bfbits(float f) {
  bf16_t h = __float2bfloat16(f);
  union { bf16_t h; short s; } u; u.h = h; return u.s;
}

// async global->LDS, 16 bytes per lane; lds must be wave-uniform, HW writes
// lds + lane*16 (cdna_hip_programming.md §5: width=16 = 874 TF lever).
DEV void gload_lds16(const bf16_t* g, bf16_t* lds) {
  __builtin_amdgcn_global_load_lds(
      (const __attribute__((address_space(1))) void*)g,
      (__attribute__((address_space(3))) void*)lds, 16, 0, 0);
}

// ---------------- elementwise fp32 -> bf16 (4 elems/thread) ----------------
__global__ __launch_bounds__(256) void k_f32_to_bf16(const float* __restrict__ in,
                                                     bf16_t* __restrict__ out) {
  size_t i = ((size_t)blockIdx.x * 256 + threadIdx.x) * 4;
  f32x4 x = *(const f32x4*)(in + i);
  short4v o;
  o[0] = bfbits(x[0]); o[1] = bfbits(x[1]); o[2] = bfbits(x[2]); o[3] = bfbits(x[3]);
  *(short4v*)((short*)out + i) = o;
}

// ---------------- transpose fp32 [R][C] -> bf16 [C][R] ----------------
__global__ __launch_bounds__(256) void k_transpose_f32_bf16(const float* __restrict__ in,
                                                            bf16_t* __restrict__ out,
                                                            int R, int C) {
  __shared__ float tile[32][33];
  int tx = threadIdx.x & 31, ty = threadIdx.x >> 5;   // 32 x 8
  int r0 = blockIdx.y * 32, c0 = blockIdx.x * 32;
  #pragma unroll
  for (int i = 0; i < 4; ++i)
    tile[ty + i * 8][tx] = in[(size_t)(r0 + ty + i * 8) * C + c0 + tx];
  __syncthreads();
  #pragma unroll
  for (int i = 0; i < 4; ++i)
    out[(size_t)(c0 + ty + i * 8) * R + r0 + tx] = __float2bfloat16(tile[tx][ty + i * 8]);
}

// ---- four square 1024x1024 transposes in one launch (z selects weight) ----
__global__ __launch_bounds__(256) void k_transpose4_f32_bf16(
    const float* __restrict__ w0, const float* __restrict__ w1,
    const float* __restrict__ w2, const float* __restrict__ w3,
    bf16_t* __restrict__ o0, bf16_t* __restrict__ o1,
    bf16_t* __restrict__ o2, bf16_t* __restrict__ o3) {
  __shared__ float tile[32][33];
  const int zz = blockIdx.z;
  const float* in = zz == 0 ? w0 : zz == 1 ? w1 : zz == 2 ? w2 : w3;
  bf16_t* out = zz == 0 ? o0 : zz == 1 ? o1 : zz == 2 ? o2 : o3;
  int tx = threadIdx.x & 31, ty = threadIdx.x >> 5;
  int r0 = blockIdx.y * 32, c0 = blockIdx.x * 32;
  #pragma unroll
  for (int i = 0; i < 4; ++i)
    tile[ty + i * 8][tx] = in[(size_t)(r0 + ty + i * 8) * 1024 + c0 + tx];
  __syncthreads();
  #pragma unroll
  for (int i = 0; i < 4; ++i)
    out[(size_t)(c0 + ty + i * 8) * 1024 + r0 + tx] = __float2bfloat16(tile[tx][ty + i * 8]);
}

// ---------------- batched transpose bf16 [R][C] -> [C][R] ----------------
__global__ __launch_bounds__(256) void k_transpose_bf16_b(const bf16_t* __restrict__ in,
                                                          bf16_t* __restrict__ out,
                                                          int R, int C, long sIn, long sOut) {
  __shared__ bf16_t tile[32][33];
  const bf16_t* inz = in + (size_t)blockIdx.z * sIn;
  bf16_t* outz = out + (size_t)blockIdx.z * sOut;
  int tx = threadIdx.x & 31, ty = threadIdx.x >> 5;
  int r0 = blockIdx.y * 32, c0 = blockIdx.x * 32;
  #pragma unroll
  for (int i = 0; i < 4; ++i)
    tile[ty + i * 8][tx] = inz[(size_t)(r0 + ty + i * 8) * C + c0 + tx];
  __syncthreads();
  #pragma unroll
  for (int i = 0; i < 4; ++i)
    outz[(size_t)(c0 + ty + i * 8) * R + r0 + tx] = tile[tx][ty + i * 8];
}

// ---------------- GEMM: C[M][N] = A[M][K](bf16) @ Bt[N][K](bf16) ----------------
// m97 structure: block 256 thr = 4 waves (2x2), wave tile 64x64, MFMA 16x16x32,
// BK=32, LINEAR LDS [128][32] (64B rows) staged via global_load_lds width 16.
// A-frag: A[m=lane&15][k=(lane>>4)*8+j]; C/D: col=lane&15, row=(lane>>4)*4+reg.
// QKV3: Bt is 3 vertically-concatenated [1024][K] weights; output routed to
// Cb + (n0>>10)*4194304 with per-tensor bias; Q (tz==0) pre-scaled by 1/8
// (exact bf16 exponent shift) so flash softmax skips the 0.125 mul.
template<int BM, int BN, bool ALPHA, bool BIAS, bool RELU, bool RESID,
         bool OUTF, bool OUTB, bool QKV3>
__global__ __launch_bounds__(256)
void k_gemm_bt(const bf16_t* __restrict__ A, const bf16_t* __restrict__ Bt,
               float* __restrict__ Cf, bf16_t* __restrict__ Cb,
               const float* __restrict__ bias, const float* __restrict__ bias2,
               const float* __restrict__ bias3, const float* __restrict__ resid,
               int Kdim, int lda, int ldb, int ldc, float alpha) {
  constexpr int BK = 32;
  constexpr int WTM = BM / 2, WTN = BN / 2;
  constexpr int MI = WTM / 16, NI = WTN / 16;
  __shared__ __align__(16) bf16_t sA[BM * BK];
  __shared__ __align__(16) bf16_t sB[BN * BK];

  const int tid = threadIdx.x;
  const int lane = tid & 63;
  const int wv = tid >> 6;
  const int wm = wv & 1, wn = wv >> 1;
  const size_t m0 = (size_t)blockIdx.y * BM;
  const size_t n0 = (size_t)blockIdx.x * BN;

  f32x4 acc[MI][NI] = {};

  // staging geometry: chunk = 16 rows = 1KB; lane l covers (row l>>2, 16B col l&3)
  const int rr = lane >> 2, cc = (lane & 3) * 8;
  const bf16_t* Arow = A + (m0 + rr) * (size_t)lda + cc;   // + chunk*16*lda + k0
  const bf16_t* Brow = Bt + (n0 + rr) * (size_t)ldb + cc;

  const int fm = wm * WTM + (lane & 15);
  const int fn = wn * WTN + (lane & 15);
  const int fk = (lane >> 4) * 8;

  for (int k0 = 0; k0 < Kdim; k0 += BK) {
    #pragma unroll
    for (int j = 0; j < BM / 64; ++j) {
      int c = j * 4 + wv;                       // chunk id 0..BM/16-1, wave-uniform
      gload_lds16(Arow + (size_t)c * 16 * lda + k0, sA + c * 512);
    }
    #pragma unroll
    for (int j = 0; j < BN / 64; ++j) {
      int c = j * 4 + wv;
      gload_lds16(Brow + (size_t)c * 16 * ldb + k0, sB + c * 512);
    }
    __syncthreads();   // drains vmcnt: LDS tiles complete

    short8 av[MI], bvv[NI];
    #pragma unroll
    for (int mi = 0; mi < MI; ++mi) av[mi] = *(const short8*)(sA + (fm + mi * 16) * BK + fk);
    #pragma unroll
    for (int ni = 0; ni < NI; ++ni) bvv[ni] = *(const short8*)(sB + (fn + ni * 16) * BK + fk);
    #pragma unroll
    for (int mi = 0; mi < MI; ++mi)
      #pragma unroll
      for (int ni = 0; ni < NI; ++ni)
        acc[mi][ni] = __builtin_amdgcn_mfma_f32_16x16x32_bf16(av[mi], bvv[ni],
                                                              acc[mi][ni], 0, 0, 0);
    __syncthreads();
  }

  // epilogue
  const int tz = QKV3 ? (int)(n0 >> 10) : 0;                    // uniform per block
  const float* bp = BIAS ? (QKV3 ? (tz == 0 ? bias : (tz == 1 ? bias2 : bias3))
                                 : bias) : nullptr;
  bf16_t* cb = QKV3 ? (Cb + (size_t)tz * 4194304) : Cb;
  const float qscale = (QKV3 && tz == 0) ? 0.125f : 1.0f;
  const int col0 = (int)n0 + wn * WTN + (lane & 15);
  const int row0 = (int)m0 + wm * WTM + ((lane >> 4) << 2);
  #pragma unroll
  for (int ni = 0; ni < NI; ++ni) {
    const int col = col0 + ni * 16;
    const int colw = QKV3 ? (col & 1023) : col;
    const float bval = BIAS ? bp[colw] : 0.0f;
    #pragma unroll
    for (int mi = 0; mi < MI; ++mi) {
      #pragma unroll
      for (int r = 0; r < 4; ++r) {
        int row = row0 + mi * 16 + r;
        float v = acc[mi][ni][r];
        if (ALPHA) v *= alpha;
        v += bval;
        if (QKV3) v *= qscale;
        size_t off = (size_t)row * ldc + colw;
        if (RESID) v += resid[off];
        if (RELU) v = fmaxf(v, 0.0f);
        if (OUTF) Cf[off] = v;
        if (OUTB) cb[off] = __float2bfloat16(v);
      }
    }
  }
}

// ---------------- fused attention: S=(Q/8)@K^T, softmax (exact, written to
// attn), ctx = P @ V. One block = 128 Q-rows of one head; 4 waves, each wave
// owns 32 rows (stats wave-local). S computed twice (stats pass + emit pass).
// T14 schedule: prefetch chunk c+2 to regs while MFMA'ing chunk c from LDS
// buffer c&1; write regs->buffer (c+1)&1; ONE barrier per chunk. sP is
// intra-wave only (own 32 rows) -> lgkmcnt fence, no barrier.
// Q,K: [64][1024][64] bf16 (stride 65536). Vt: [64][64][1024] bf16.
// attn: [64][1024][1024] fp32. ctx: [64][1024][64] bf16.
__global__ __launch_bounds__(256) void k_flash_attn(const bf16_t* __restrict__ Qb,
                                                    const bf16_t* __restrict__ Kb,
                                                    const bf16_t* __restrict__ Vt,
                                                    float* __restrict__ attn,
                                                    bf16_t* __restrict__ ctx) {
  constexpr int LP = 72;  // row pad: 144B rows, 16B aligned, 2-way-max conflicts (free)
  __shared__ __align__(16) bf16_t sQ[128][LP];
  __shared__ __align__(16) bf16_t sK[2][64][LP];
  __shared__ __align__(16) bf16_t sV[2][64][LP];
  __shared__ __align__(16) bf16_t sP[128][LP];

  const int tid = threadIdx.x;
  const int lane = tid & 63;
  const int wv = tid >> 6;            // wave owns rows wv*32 .. wv*32+31
  const int z = blockIdx.y;
  const int m0 = blockIdx.x * 128;

  const bf16_t* Qz = Qb + (size_t)z * 65536;
  const bf16_t* Kz = Kb + (size_t)z * 65536;
  const bf16_t* Vz = Vt + (size_t)z * 65536;
  float* az = attn + (size_t)z * 1048576;
  bf16_t* cz = ctx + (size_t)z * 65536;

  // staging geometry: thread covers rows j*32 + (tid>>3), 16B col (tid&7)*8
  const int sr = tid >> 3, sc = (tid & 7) * 8;

  // stage Q tile [128][64]
  #pragma unroll
  for (int j = 0; j < 4; ++j)
    *(short8*)(&sQ[j * 32 + sr][sc]) =
        *(const short8*)(Qz + (size_t)(m0 + j * 32 + sr) * 64 + sc);
  __syncthreads();

  const int fr = lane & 15;           // frag row/col index
  const int fk = (lane >> 4) * 8;     // frag k offset
  const int crow = (lane >> 4) << 2;  // C/D row base

  // preload Q A-frags (sQ read-only after; K=64 -> 2 k-steps)
  short8 qf[2][2];
  #pragma unroll
  for (int mi = 0; mi < 2; ++mi)
    #pragma unroll
    for (int ks = 0; ks < 2; ++ks)
      qf[mi][ks] = *(const short8*)(&sQ[wv * 32 + mi * 16 + fr][ks * 32 + fk]);

  float m_run[2][4], s_run[2][4];
  #pragma unroll
  for (int mi = 0; mi < 2; ++mi)
    #pragma unroll
    for (int r = 0; r < 4; ++r) { m_run[mi][r] = -1e30f; s_run[mi][r] = 0.0f; }

  short8 kreg[2], vreg[2];

  // ---- pass 1: online row max / sum-exp over all 16 K-chunks ----
  #pragma unroll
  for (int j = 0; j < 2; ++j)
    kreg[j] = *(const short8*)(Kz + (size_t)(j * 32 + sr) * 64 + sc);
  #pragma unroll
  for (int j = 0; j < 2; ++j)
    *(short8*)(&sK[0][j * 32 + sr][sc]) = kreg[j];
  #pragma unroll
  for (int j = 0; j < 2; ++j)
    kreg[j] = *(const short8*)(Kz + (size_t)(64 + j * 32 + sr) * 64 + sc);
  __syncthreads();

  for (int c = 0; c < 16; ++c) {
    const int cur = c & 1;
    if (c + 1 < 16) {                 // publish chunk c+1 (buffer cur^1: last read at c-1)
      #pragma unroll
      for (int j = 0; j < 2; ++j)
        *(short8*)(&sK[cur ^ 1][j * 32 + sr][sc]) = kreg[j];
    }
    if (c + 2 < 16) {                 // prefetch chunk c+2; latency hides under MFMA+stats
      #pragma unroll
      for (int j = 0; j < 2; ++j)
        kreg[j] = *(const short8*)(Kz + (size_t)((c + 2) * 64 + j * 32 + sr) * 64 + sc);
    }
    f32x4 acc[2][4] = {};
    #pragma unroll
    for (int ks = 0; ks < 2; ++ks) {
      short8 bf[4];
      #pragma unroll
      for (int ni = 0; ni < 4; ++ni)
        bf[ni] = *(const short8*)(&sK[cur][ni * 16 + fr][ks * 32 + fk]);
      #pragma unroll
      for (int mi = 0; mi < 2; ++mi)
        #pragma unroll
        for (int ni = 0; ni < 4; ++ni)
          acc[mi][ni] = __builtin_amdgcn_mfma_f32_16x16x32_bf16(qf[mi][ks], bf[ni],
                                                                acc[mi][ni], 0, 0, 0);
    }
    #pragma unroll
    for (int mi = 0; mi < 2; ++mi)
      #pragma unroll
      for (int r = 0; r < 4; ++r) {
        float mx = acc[mi][0][r];
        #pragma unroll
        for (int ni = 1; ni < 4; ++ni) mx = fmaxf(mx, acc[mi][ni][r]);
        #pragma unroll
        for (int o = 1; o < 16; o <<= 1) mx = fmaxf(mx, __shfl_xor(mx, o, 64));
        float mn = fmaxf(m_run[mi][r], mx);
        float se = 0.0f;
        #pragma unroll
        for (int ni = 0; ni < 4; ++ni) se += __expf(acc[mi][ni][r] - mn);
        #pragma unroll
        for (int o = 1; o < 16; o <<= 1) se += __shfl_xor(se, o, 64);
        s_run[mi][r] = s_run[mi][r] * __expf(m_run[mi][r] - mn) + se;
        m_run[mi][r] = mn;
      }
    __syncthreads();                  // publishes buffer cur^1 for next iter
  }

  float inv_s[2][4];
  #pragma unroll
  for (int mi = 0; mi < 2; ++mi)
    #pragma unroll
    for (int r = 0; r < 4; ++r) inv_s[mi][r] = 1.0f / s_run[mi][r];

  // ---- pass 2: recompute S, emit exact softmax to attn, accumulate P@V ----
  #pragma unroll
  for (int j = 0; j < 2; ++j) {
    kreg[j] = *(const short8*)(Kz + (size_t)(j * 32 + sr) * 64 + sc);
    vreg[j] = *(const short8*)(Vz + (size_t)(j * 32 + sr) * 1024 + sc);
  }
  #pragma unroll
  for (int j = 0; j < 2; ++j) {
    *(short8*)(&sK[0][j * 32 + sr][sc]) = kreg[j];
    *(short8*)(&sV[0][j * 32 + sr][sc]) = vreg[j];
  }
  #pragma unroll
  for (int j = 0; j < 2; ++j) {
    kreg[j] = *(const short8*)(Kz + (size_t)(64 + j * 32 + sr) * 64 + sc);
    vreg[j] = *(const short8*)(Vz + (size_t)(j * 32 + sr) * 1024 + 64 + sc);
  }
  __syncthreads();

  f32x4 cacc[2][4] = {};
  for (int c = 0; c < 16; ++c) {
    const int cur = c & 1;
    const int c0 = c * 64;
    if (c + 1 < 16) {
      #pragma unroll
      for (int j = 0; j < 2; ++j) {
        *(short8*)(&sK[cur ^ 1][j * 32 + sr][sc]) = kreg[j];
        *(short8*)(&sV[cur ^ 1][j * 32 + sr][sc]) = vreg[j];
      }
    }
    if (c + 2 < 16) {
      #pragma unroll
      for (int j = 0; j < 2; ++j) {
        kreg[j] = *(const short8*)(Kz + (size_t)((c + 2) * 64 + j * 32 + sr) * 64 + sc);
        vreg[j] = *(const short8*)(Vz + (size_t)(j * 32 + sr) * 1024 + (c + 2) * 64 + sc);
      }
    }
    f32x4 acc[2][4] = {};
    #pragma unroll
    for (int ks = 0; ks < 2; ++ks) {
      short8 bf[4];
      #pragma unroll
      for (int ni = 0; ni < 4; ++ni)
        bf[ni] = *(const short8*)(&sK[cur][ni * 16 + fr][ks * 32 + fk]);
      #pragma unroll
      for (int mi = 0; mi < 2; ++mi)
        #pragma unroll
        for (int ni = 0; ni < 4; ++ni)
          acc[mi][ni] = __builtin_amdgcn_mfma_f32_16x16x32_bf16(qf[mi][ks], bf[ni],
                                                                acc[mi][ni], 0, 0, 0);
    }
    // normalized P: global write (mandatory output) + bf16 into LDS for PV
    #pragma unroll
    for (int mi = 0; mi < 2; ++mi)
      #pragma unroll
      for (int ni = 0; ni < 4; ++ni)
        #pragma unroll
        for (int r = 0; r < 4; ++r) {
          int row = wv * 32 + mi * 16 + crow + r;
          float p = __expf(acc[mi][ni][r] - m_run[mi][r]) * inv_s[mi][r];
          az[(size_t)(m0 + row) * 1024 + c0 + ni * 16 + fr] = p;
          sP[row][ni * 16 + fr] = __float2bfloat16(p);
        }
    // sP is read only by the wave that wrote it (rows wv*32..+31): intra-wave
    // fence suffices. asm wait orders the ds_writes; sched_barrier stops the
    // compiler hoisting the (per-thread provably-disjoint) sP reads above it.
    asm volatile("s_waitcnt lgkmcnt(0)" ::: "memory");
    __builtin_amdgcn_sched_barrier(0);
    #pragma unroll
    for (int ks = 0; ks < 2; ++ks) {
      short8 pa[2], vb[4];
      #pragma unroll
      for (int mi = 0; mi < 2; ++mi)
        pa[mi] = *(const short8*)(&sP[wv * 32 + mi * 16 + fr][ks * 32 + fk]);
      #pragma unroll
      for (int ni = 0; ni < 4; ++ni)
        vb[ni] = *(const short8*)(&sV[cur][ni * 16 + fr][ks * 32 + fk]);
      #pragma unroll
      for (int mi = 0; mi < 2; ++mi)
        #pragma unroll
        for (int ni = 0; ni < 4; ++ni)
          cacc[mi][ni] = __builtin_amdgcn_mfma_f32_16x16x32_bf16(pa[mi], vb[ni],
                                                                 cacc[mi][ni], 0, 0, 0);
    }
    __syncthreads();                  // publishes K/V buffer cur^1 for next iter
  }

  // ctx write: [1024][64] bf16 per head
  #pragma unroll
  for (int mi = 0; mi < 2; ++mi)
    #pragma unroll
    for (int ni = 0; ni < 4; ++ni)
      #pragma unroll
      for (int r = 0; r < 4; ++r) {
        int row = wv * 32 + mi * 16 + crow + r;
        cz[(size_t)(m0 + row) * 64 + ni * 16 + fr] = __float2bfloat16(cacc[mi][ni][r]);
      }
}

// ---------------- row layernorm, width 1024, in place (+optional bf16 copy) -------
__global__ __launch_bounds__(256) void k_layernorm(float* __restrict__ io,
                                                   bf16_t* __restrict__ ob,
                                                   const float* __restrict__ g,
                                                   const float* __restrict__ bta) {
  float* r = io + (size_t)blockIdx.x * 1024;
  const int t = threadIdx.x;
  f32x4 x = *(const f32x4*)(r + t * 4);
  float s = x[0] + x[1] + x[2] + x[3];
  float s2 = x[0] * x[0] + x[1] * x[1] + x[2] * x[2] + x[3] * x[3];
  #pragma unroll
  for (int o = 32; o > 0; o >>= 1) { s += __shfl_xor(s, o, 64); s2 += __shfl_xor(s2, o, 64); }
  __shared__ float as[4], as2[4];
  if ((t & 63) == 0) { as[t >> 6] = s; as2[t >> 6] = s2; }
  __syncthreads();
  s = as[0] + as[1] + as[2] + as[3];
  s2 = as2[0] + as2[1] + as2[2] + as2[3];
  float mu = s * (1.0f / 1024.0f);
  float var = s2 * (1.0f / 1024.0f) - mu * mu;
  float rs = rsqrtf(var + 1e-5f);
  f32x4 gg = *(const f32x4*)(g + t * 4);
  f32x4 bb = *(const f32x4*)(bta + t * 4);
  f32x4 y;
  #pragma unroll
  for (int i = 0; i < 4; ++i) y[i] = (x[i] - mu) * rs * gg[i] + bb[i];
  *(f32x4*)(r + t * 4) = y;
  if (ob) {
    short4v o4;
    o4[0] = bfbits(y[0]); o4[1] = bfbits(y[1]); o4[2] = bfbits(y[2]); o4[3] = bfbits(y[3]);
    *(short4v*)((short*)ob + (size_t)blockIdx.x * 1024 + t * 4) = o4;
  }
}

extern "C" void kernel_launch(void* const* d_in, const int* in_sizes, int n_in,
                              void* d_out, int out_size, void* d_ws, size_t ws_size,
                              hipStream_t stream) {
  (void)in_sizes; (void)n_in; (void)out_size;
  const float* inputs = (const float*)d_in[0];
  const float* Wq = (const float*)d_in[1];  const float* bq = (const float*)d_in[2];
  const float* Wk = (const float*)d_in[3];  const float* bk = (const float*)d_in[4];
  const float* Wv = (const float*)d_in[5];  const float* bv = (const float*)d_in[6];
  const float* Wo = (const float*)d_in[7];  const float* bo = (const float*)d_in[8];
  const float* ln1g = (const float*)d_in[9];  const float* ln1b = (const float*)d_in[10];
  const float* W1 = (const float*)d_in[11]; const float* b1 = (const float*)d_in[12];
  const float* W2 = (const float*)d_in[13]; const float* b2 = (const float*)d_in[14];
  const float* ln2g = (const float*)d_in[15]; const float* ln2b = (const float*)d_in[16];

  const size_t MB = 1ull << 20;
  if (ws_size < 96 * MB) return;  // layout below needs 96 MB scratch

  char* ws = (char*)d_ws;
  bf16_t* WQT  = (bf16_t*)(ws + 0 * MB);   // [1024][1024]; WQT/WKT/WVT contiguous
  bf16_t* WKT  = (bf16_t*)(ws + 2 * MB);   //   -> fused QKV sees [3072][1024]
  bf16_t* WVT  = (bf16_t*)(ws + 4 * MB);
  bf16_t* WOT  = (bf16_t*)(ws + 6 * MB);
  bf16_t* W1T  = (bf16_t*)(ws + 8 * MB);   // [4096][1024]
  bf16_t* W2T  = (bf16_t*)(ws + 16 * MB);  // [1024][4096]
  bf16_t* XB   = (bf16_t*)(ws + 24 * MB);  // [4096][1024]; dead after QKV
  bf16_t* QB   = (bf16_t*)(ws + 32 * MB);  // QB/KB/VB contiguous, 8MB stride
  bf16_t* KB   = (bf16_t*)(ws + 40 * MB);
  bf16_t* VB   = (bf16_t*)(ws + 48 * MB);  // dead after Vt transpose
  bf16_t* VT   = (bf16_t*)(ws + 56 * MB);  // [64 batches][64][1024]; dead after flash
  bf16_t* CTX  = (bf16_t*)(ws + 24 * MB);  // reuse XB slot
  float*  OUT1F = (float*)(ws + 40 * MB);  // fp32 [4096][1024] (reuse KB+VB slots)
  bf16_t* OUT1B = (bf16_t*)(ws + 32 * MB); // reuse QB slot
  bf16_t* HB   = (bf16_t*)(ws + 64 * MB);  // [4096][4096]

  float* outF = (float*)d_out;             // [4096][1024]
  float* attn = outF + 4194304;            // [64][1024][1024] fp32 (final output region)

  // --- prep: bf16 input copy + transposed bf16 weights ---
  k_f32_to_bf16<<<4096, 256, 0, stream>>>(inputs, XB);
  k_transpose4_f32_bf16<<<dim3(32, 32, 4), 256, 0, stream>>>(Wq, Wk, Wv, Wo,
                                                             WQT, WKT, WVT, WOT);
  k_transpose_f32_bf16<<<dim3(128, 32), 256, 0, stream>>>(W1, W1T, 1024, 4096);
  k_transpose_f32_bf16<<<dim3(32, 128), 256, 0, stream>>>(W2, W2T, 4096, 1024);

  // --- fused QKV: [4096,1024] @ [1024,3072] -> QB/KB/VB (Q pre-scaled 1/8) ---
  k_gemm_bt<128, 128, false, true, false, false, false, true, true>
      <<<dim3(24, 32), 256, 0, stream>>>(XB, WQT, nullptr, QB, bq, bk, bv, nullptr,
                                         1024, 1024, 1024, 1024, 1.0f);

  // --- per-"head" V transpose: [1024][64] -> [64][1024], 64 batches ---
  k_transpose_bf16_b<<<dim3(2, 32, 64), 256, 0, stream>>>(VB, VT, 1024, 64, 65536, 65536);

  // --- fused scores+softmax+PV; writes exact attn fp32 + ctx bf16 ---
  k_flash_attn<<<dim3(8, 64), 256, 0, stream>>>(QB, KB, VT, attn, CTX);

  // --- out-proj + bias + residual(inputs) -> OUT1F fp32 ---
  k_gemm_bt<128, 128, false, true, false, true, true, false, false>
      <<<dim3(8, 32), 256, 0, stream>>>(CTX, WOT, OUT1F, nullptr, bo, nullptr, nullptr,
                                        inputs, 1024, 1024, 1024, 1024, 1.0f);

  // --- LN1 in place + bf16 copy ---
  k_layernorm<<<4096, 256, 0, stream>>>(OUT1F, OUT1B, ln1g, ln1b);

  // --- FFN1: relu(out1 @ W1 + b1) -> HB bf16 [4096][4096] ---
  k_gemm_bt<128, 128, false, true, true, false, false, true, false>
      <<<dim3(32, 32), 256, 0, stream>>>(OUT1B, W1T, nullptr, HB, b1, nullptr, nullptr,
                                         nullptr, 1024, 1024, 1024, 4096, 1.0f);

  // --- FFN2: HB @ W2 + b2 + out1 -> d_out[0:4M] fp32 ---
  k_gemm_bt<128, 128, false, true, false, true, true, false, false>
      <<<dim3(8, 32), 256, 0, stream>>>(HB, W2T, outF, nullptr, b2, nullptr, nullptr,
                                        OUT1F, 4096, 4096, 4096, 1024, 1.0f);

  // --- LN2 in place on d_out ---
  k_layernorm<<<4096, 256, 0, stream>>>(outF, nullptr, ln2g, ln2b);
}

// Round 4
// 666.377 us; speedup vs baseline: 1.1437x; 1.0416x over previous
//
#include <hip/hip_runtime.h>
#include <hip/hip_bf16.h>
#include <stdint.h>

// EncoderLayer on MI355X: bf16 MFMA GEMMs + fp32 softmax/LN epilogues.
// Pipeline: prep(convert/transpose) -> fused QKV (Q pre-scaled 1/8) -> Vt ->
//           flash(scores+softmax+PV, writes exact attn; T14 async-stage + dbuf)
//           -> Wo+resid -> LN1 -> FFN1(relu) -> FFN2+resid -> LN2.
// GEMM: global_load_lds width=16 staging (m97), T1 XCD swizzle (grids %8==0),
//       1-block/CU GEMMs (Wo, FFN2) use BN=64 for 2 blocks/CU.

using bf16_t  = __hip_bfloat16;
using short8  = __attribute__((ext_vector_type(8))) short;
using short4v = __attribute__((ext_vector_type(4))) short;
using f32x4   = __attribute__((ext_vector_type(4))) float;

#define DEV static __device__ __forceinline__

DEV short bfbits(float f) {
  bf16_t h = __float2bfloat16(f);
  union { bf16_t h; short s; } u; u.h = h; return u.s;
}

// async global->LDS, 16 bytes per lane; lds must be wave-uniform, HW writes
// lds + lane*16 (cdna_hip_programming.md §5: width=16 = 874 TF lever).
DEV void gload_lds16(const bf16_t* g, bf16_t* lds) {
  __builtin_amdgcn_global_load_lds(
      (const __attribute__((address_space(1))) void*)g,
      (__attribute__((address_space(3))) void*)lds, 16, 0, 0);
}

// ---------------- elementwise fp32 -> bf16 (4 elems/thread) ----------------
__global__ __launch_bounds__(256) void k_f32_to_bf16(const float* __restrict__ in,
                                                     bf16_t* __restrict__ out) {
  size_t i = ((size_t)blockIdx.x * 256 + threadIdx.x) * 4;
  f32x4 x = *(const f32x4*)(in + i);
  short4v o;
  o[0] = bfbits(x[0]); o[1] = bfbits(x[1]); o[2] = bfbits(x[2]); o[3] = bfbits(x[3]);
  *(short4v*)((short*)out + i) = o;
}

// ---------------- transpose fp32 [R][C] -> bf16 [C][R] ----------------
__global__ __launch_bounds__(256) void k_transpose_f32_bf16(const float* __restrict__ in,
                                                            bf16_t* __restrict__ out,
                                                            int R, int C) {
  __shared__ float tile[32][33];
  int tx = threadIdx.x & 31, ty = threadIdx.x >> 5;   // 32 x 8
  int r0 = blockIdx.y * 32, c0 = blockIdx.x * 32;
  #pragma unroll
  for (int i = 0; i < 4; ++i)
    tile[ty + i * 8][tx] = in[(size_t)(r0 + ty + i * 8) * C + c0 + tx];
  __syncthreads();
  #pragma unroll
  for (int i = 0; i < 4; ++i)
    out[(size_t)(c0 + ty + i * 8) * R + r0 + tx] = __float2bfloat16(tile[tx][ty + i * 8]);
}

// ---- four square 1024x1024 transposes in one launch (z selects weight) ----
__global__ __launch_bounds__(256) void k_transpose4_f32_bf16(
    const float* __restrict__ w0, const float* __restrict__ w1,
    const float* __restrict__ w2, const float* __restrict__ w3,
    bf16_t* __restrict__ o0, bf16_t* __restrict__ o1,
    bf16_t* __restrict__ o2, bf16_t* __restrict__ o3) {
  __shared__ float tile[32][33];
  const int zz = blockIdx.z;
  const float* in = zz == 0 ? w0 : zz == 1 ? w1 : zz == 2 ? w2 : w3;
  bf16_t* out = zz == 0 ? o0 : zz == 1 ? o1 : zz == 2 ? o2 : o3;
  int tx = threadIdx.x & 31, ty = threadIdx.x >> 5;
  int r0 = blockIdx.y * 32, c0 = blockIdx.x * 32;
  #pragma unroll
  for (int i = 0; i < 4; ++i)
    tile[ty + i * 8][tx] = in[(size_t)(r0 + ty + i * 8) * 1024 + c0 + tx];
  __syncthreads();
  #pragma unroll
  for (int i = 0; i < 4; ++i)
    out[(size_t)(c0 + ty + i * 8) * 1024 + r0 + tx] = __float2bfloat16(tile[tx][ty + i * 8]);
}

// ---------------- batched transpose bf16 [R][C] -> [C][R] ----------------
__global__ __launch_bounds__(256) void k_transpose_bf16_b(const bf16_t* __restrict__ in,
                                                          bf16_t* __restrict__ out,
                                                          int R, int C, long sIn, long sOut) {
  __shared__ bf16_t tile[32][33];
  const bf16_t* inz = in + (size_t)blockIdx.z * sIn;
  bf16_t* outz = out + (size_t)blockIdx.z * sOut;
  int tx = threadIdx.x & 31, ty = threadIdx.x >> 5;
  int r0 = blockIdx.y * 32, c0 = blockIdx.x * 32;
  #pragma unroll
  for (int i = 0; i < 4; ++i)
    tile[ty + i * 8][tx] = inz[(size_t)(r0 + ty + i * 8) * C + c0 + tx];
  __syncthreads();
  #pragma unroll
  for (int i = 0; i < 4; ++i)
    outz[(size_t)(c0 + ty + i * 8) * R + r0 + tx] = tile[tx][ty + i * 8];
}

// ---------------- GEMM: C[M][N] = A[M][K](bf16) @ Bt[N][K](bf16) ----------------
// m97 structure: block 256 thr = 4 waves (2x2), wave tile (BM/2)x(BN/2),
// MFMA 16x16x32, BK=32, LINEAR LDS staged via global_load_lds width 16.
// T1: bijective XCD swizzle of linear block id (REQUIRES grid total %8==0):
// consecutive same-XCD blocks share the A m-panel -> XCD-L2 reuse.
// A-frag: A[m=lane&15][k=(lane>>4)*8+j]; C/D: col=lane&15, row=(lane>>4)*4+reg.
// QKV3: Bt is 3 vertically-concatenated [1024][K] weights; output routed to
// Cb + (n0>>10)*4194304 with per-tensor bias; Q (tz==0) pre-scaled by 1/8.
template<int BM, int BN, bool ALPHA, bool BIAS, bool RELU, bool RESID,
         bool OUTF, bool OUTB, bool QKV3>
__global__ __launch_bounds__(256)
void k_gemm_bt(const bf16_t* __restrict__ A, const bf16_t* __restrict__ Bt,
               float* __restrict__ Cf, bf16_t* __restrict__ Cb,
               const float* __restrict__ bias, const float* __restrict__ bias2,
               const float* __restrict__ bias3, const float* __restrict__ resid,
               int Kdim, int lda, int ldb, int ldc, float alpha) {
  constexpr int BK = 32;
  constexpr int WTM = BM / 2, WTN = BN / 2;
  constexpr int MI = WTM / 16, NI = WTN / 16;
  __shared__ __align__(16) bf16_t sA[BM * BK];
  __shared__ __align__(16) bf16_t sB[BN * BK];

  const int tid = threadIdx.x;
  const int lane = tid & 63;
  const int wv = tid >> 6;
  const int wm = wv & 1, wn = wv >> 1;

  // T1 XCD swizzle (bijective since total %8 == 0 for all call sites)
  const int gx = gridDim.x;
  const int total = gx * gridDim.y;
  const int lin = blockIdx.y * gx + blockIdx.x;
  const int swz = (lin & 7) * (total >> 3) + (lin >> 3);
  const size_t m0 = (size_t)(swz / gx) * BM;
  const size_t n0 = (size_t)(swz % gx) * BN;

  f32x4 acc[MI][NI] = {};

  // staging geometry: chunk = 16 rows = 1KB; lane l covers (row l>>2, 16B col l&3)
  const int rr = lane >> 2, cc = (lane & 3) * 8;
  const bf16_t* Arow = A + (m0 + rr) * (size_t)lda + cc;   // + chunk*16*lda + k0
  const bf16_t* Brow = Bt + (n0 + rr) * (size_t)ldb + cc;

  const int fm = wm * WTM + (lane & 15);
  const int fn = wn * WTN + (lane & 15);
  const int fk = (lane >> 4) * 8;

  for (int k0 = 0; k0 < Kdim; k0 += BK) {
    #pragma unroll
    for (int j = 0; j < BM / 64; ++j) {
      int c = j * 4 + wv;                       // chunk id, wave-uniform
      gload_lds16(Arow + (size_t)c * 16 * lda + k0, sA + c * 512);
    }
    #pragma unroll
    for (int j = 0; j < BN / 64; ++j) {
      int c = j * 4 + wv;
      gload_lds16(Brow + (size_t)c * 16 * ldb + k0, sB + c * 512);
    }
    __syncthreads();   // drains vmcnt: LDS tiles complete

    short8 av[MI], bvv[NI];
    #pragma unroll
    for (int mi = 0; mi < MI; ++mi) av[mi] = *(const short8*)(sA + (fm + mi * 16) * BK + fk);
    #pragma unroll
    for (int ni = 0; ni < NI; ++ni) bvv[ni] = *(const short8*)(sB + (fn + ni * 16) * BK + fk);
    #pragma unroll
    for (int mi = 0; mi < MI; ++mi)
      #pragma unroll
      for (int ni = 0; ni < NI; ++ni)
        acc[mi][ni] = __builtin_amdgcn_mfma_f32_16x16x32_bf16(av[mi], bvv[ni],
                                                              acc[mi][ni], 0, 0, 0);
    __syncthreads();
  }

  // epilogue
  const int tz = QKV3 ? (int)(n0 >> 10) : 0;                    // uniform per block
  const float* bp = BIAS ? (QKV3 ? (tz == 0 ? bias : (tz == 1 ? bias2 : bias3))
                                 : bias) : nullptr;
  bf16_t* cb = QKV3 ? (Cb + (size_t)tz * 4194304) : Cb;
  const float qscale = (QKV3 && tz == 0) ? 0.125f : 1.0f;
  const int col0 = (int)n0 + wn * WTN + (lane & 15);
  const int row0 = (int)m0 + wm * WTM + ((lane >> 4) << 2);
  #pragma unroll
  for (int ni = 0; ni < NI; ++ni) {
    const int col = col0 + ni * 16;
    const int colw = QKV3 ? (col & 1023) : col;
    const float bval = BIAS ? bp[colw] : 0.0f;
    #pragma unroll
    for (int mi = 0; mi < MI; ++mi) {
      #pragma unroll
      for (int r = 0; r < 4; ++r) {
        int row = row0 + mi * 16 + r;
        float v = acc[mi][ni][r];
        if (ALPHA) v *= alpha;
        v += bval;
        if (QKV3) v *= qscale;
        size_t off = (size_t)row * ldc + colw;
        if (RESID) v += resid[off];
        if (RELU) v = fmaxf(v, 0.0f);
        if (OUTF) Cf[off] = v;
        if (OUTB) cb[off] = __float2bfloat16(v);
      }
    }
  }
}

// ---------------- fused attention: S=(Q/8)@K^T, softmax (exact, written to
// attn), ctx = P @ V. One block = 128 Q-rows of one head; 4 waves, each wave
// owns 32 rows (stats wave-local). S computed twice (stats pass + emit pass).
// T14 schedule: prefetch chunk c+2 to regs while MFMA'ing chunk c from LDS
// buffer c&1; write regs->buffer (c+1)&1; ONE barrier per chunk. sP is
// intra-wave only -> lgkmcnt fence, no barrier. T5 setprio around MFMA.
// attn stores are nontemporal (write-only stream; keep K/V in cache).
__global__ __launch_bounds__(256) void k_flash_attn(const bf16_t* __restrict__ Qb,
                                                    const bf16_t* __restrict__ Kb,
                                                    const bf16_t* __restrict__ Vt,
                                                    float* __restrict__ attn,
                                                    bf16_t* __restrict__ ctx) {
  constexpr int LP = 72;  // row pad: 144B rows, 16B aligned, 2-way-max conflicts (free)
  __shared__ __align__(16) bf16_t sQ[128][LP];
  __shared__ __align__(16) bf16_t sK[2][64][LP];
  __shared__ __align__(16) bf16_t sV[2][64][LP];
  __shared__ __align__(16) bf16_t sP[128][LP];

  const int tid = threadIdx.x;
  const int lane = tid & 63;
  const int wv = tid >> 6;            // wave owns rows wv*32 .. wv*32+31
  const int z = blockIdx.y;
  const int m0 = blockIdx.x * 128;

  const bf16_t* Qz = Qb + (size_t)z * 65536;
  const bf16_t* Kz = Kb + (size_t)z * 65536;
  const bf16_t* Vz = Vt + (size_t)z * 65536;
  float* az = attn + (size_t)z * 1048576;
  bf16_t* cz = ctx + (size_t)z * 65536;

  // staging geometry: thread covers rows j*32 + (tid>>3), 16B col (tid&7)*8
  const int sr = tid >> 3, sc = (tid & 7) * 8;

  // stage Q tile [128][64]
  #pragma unroll
  for (int j = 0; j < 4; ++j)
    *(short8*)(&sQ[j * 32 + sr][sc]) =
        *(const short8*)(Qz + (size_t)(m0 + j * 32 + sr) * 64 + sc);
  __syncthreads();

  const int fr = lane & 15;           // frag row/col index
  const int fk = (lane >> 4) * 8;     // frag k offset
  const int crow = (lane >> 4) << 2;  // C/D row base

  // preload Q A-frags (sQ read-only after; K=64 -> 2 k-steps)
  short8 qf[2][2];
  #pragma unroll
  for (int mi = 0; mi < 2; ++mi)
    #pragma unroll
    for (int ks = 0; ks < 2; ++ks)
      qf[mi][ks] = *(const short8*)(&sQ[wv * 32 + mi * 16 + fr][ks * 32 + fk]);

  float m_run[2][4], s_run[2][4];
  #pragma unroll
  for (int mi = 0; mi < 2; ++mi)
    #pragma unroll
    for (int r = 0; r < 4; ++r) { m_run[mi][r] = -1e30f; s_run[mi][r] = 0.0f; }

  short8 kreg[2], vreg[2];

  // ---- pass 1: online row max / sum-exp over all 16 K-chunks ----
  #pragma unroll
  for (int j = 0; j < 2; ++j)
    kreg[j] = *(const short8*)(Kz + (size_t)(j * 32 + sr) * 64 + sc);
  #pragma unroll
  for (int j = 0; j < 2; ++j)
    *(short8*)(&sK[0][j * 32 + sr][sc]) = kreg[j];
  #pragma unroll
  for (int j = 0; j < 2; ++j)
    kreg[j] = *(const short8*)(Kz + (size_t)(64 + j * 32 + sr) * 64 + sc);
  __syncthreads();

  for (int c = 0; c < 16; ++c) {
    const int cur = c & 1;
    if (c + 1 < 16) {                 // publish chunk c+1 (buffer cur^1: last read at c-1)
      #pragma unroll
      for (int j = 0; j < 2; ++j)
        *(short8*)(&sK[cur ^ 1][j * 32 + sr][sc]) = kreg[j];
    }
    if (c + 2 < 16) {                 // prefetch chunk c+2; latency hides under MFMA+stats
      #pragma unroll
      for (int j = 0; j < 2; ++j)
        kreg[j] = *(const short8*)(Kz + (size_t)((c + 2) * 64 + j * 32 + sr) * 64 + sc);
    }
    f32x4 acc[2][4] = {};
    __builtin_amdgcn_s_setprio(1);
    #pragma unroll
    for (int ks = 0; ks < 2; ++ks) {
      short8 bf[4];
      #pragma unroll
      for (int ni = 0; ni < 4; ++ni)
        bf[ni] = *(const short8*)(&sK[cur][ni * 16 + fr][ks * 32 + fk]);
      #pragma unroll
      for (int mi = 0; mi < 2; ++mi)
        #pragma unroll
        for (int ni = 0; ni < 4; ++ni)
          acc[mi][ni] = __builtin_amdgcn_mfma_f32_16x16x32_bf16(qf[mi][ks], bf[ni],
                                                                acc[mi][ni], 0, 0, 0);
    }
    __builtin_amdgcn_s_setprio(0);
    #pragma unroll
    for (int mi = 0; mi < 2; ++mi)
      #pragma unroll
      for (int r = 0; r < 4; ++r) {
        float mx = acc[mi][0][r];
        #pragma unroll
        for (int ni = 1; ni < 4; ++ni) mx = fmaxf(mx, acc[mi][ni][r]);
        #pragma unroll
        for (int o = 1; o < 16; o <<= 1) mx = fmaxf(mx, __shfl_xor(mx, o, 64));
        float mn = fmaxf(m_run[mi][r], mx);
        float se = 0.0f;
        #pragma unroll
        for (int ni = 0; ni < 4; ++ni) se += __expf(acc[mi][ni][r] - mn);
        #pragma unroll
        for (int o = 1; o < 16; o <<= 1) se += __shfl_xor(se, o, 64);
        s_run[mi][r] = s_run[mi][r] * __expf(m_run[mi][r] - mn) + se;
        m_run[mi][r] = mn;
      }
    __syncthreads();                  // publishes buffer cur^1 for next iter
  }

  float inv_s[2][4];
  #pragma unroll
  for (int mi = 0; mi < 2; ++mi)
    #pragma unroll
    for (int r = 0; r < 4; ++r) inv_s[mi][r] = 1.0f / s_run[mi][r];

  // ---- pass 2: recompute S, emit exact softmax to attn, accumulate P@V ----
  #pragma unroll
  for (int j = 0; j < 2; ++j) {
    kreg[j] = *(const short8*)(Kz + (size_t)(j * 32 + sr) * 64 + sc);
    vreg[j] = *(const short8*)(Vz + (size_t)(j * 32 + sr) * 1024 + sc);
  }
  #pragma unroll
  for (int j = 0; j < 2; ++j) {
    *(short8*)(&sK[0][j * 32 + sr][sc]) = kreg[j];
    *(short8*)(&sV[0][j * 32 + sr][sc]) = vreg[j];
  }
  #pragma unroll
  for (int j = 0; j < 2; ++j) {
    kreg[j] = *(const short8*)(Kz + (size_t)(64 + j * 32 + sr) * 64 + sc);
    vreg[j] = *(const short8*)(Vz + (size_t)(j * 32 + sr) * 1024 + 64 + sc);
  }
  __syncthreads();

  f32x4 cacc[2][4] = {};
  for (int c = 0; c < 16; ++c) {
    const int cur = c & 1;
    const int c0 = c * 64;
    if (c + 1 < 16) {
      #pragma unroll
      for (int j = 0; j < 2; ++j) {
        *(short8*)(&sK[cur ^ 1][j * 32 + sr][sc]) = kreg[j];
        *(short8*)(&sV[cur ^ 1][j * 32 + sr][sc]) = vreg[j];
      }
    }
    if (c + 2 < 16) {
      #pragma unroll
      for (int j = 0; j < 2; ++j) {
        kreg[j] = *(const short8*)(Kz + (size_t)((c + 2) * 64 + j * 32 + sr) * 64 + sc);
        vreg[j] = *(const short8*)(Vz + (size_t)(j * 32 + sr) * 1024 + (c + 2) * 64 + sc);
      }
    }
    f32x4 acc[2][4] = {};
    __builtin_amdgcn_s_setprio(1);
    #pragma unroll
    for (int ks = 0; ks < 2; ++ks) {
      short8 bf[4];
      #pragma unroll
      for (int ni = 0; ni < 4; ++ni)
        bf[ni] = *(const short8*)(&sK[cur][ni * 16 + fr][ks * 32 + fk]);
      #pragma unroll
      for (int mi = 0; mi < 2; ++mi)
        #pragma unroll
        for (int ni = 0; ni < 4; ++ni)
          acc[mi][ni] = __builtin_amdgcn_mfma_f32_16x16x32_bf16(qf[mi][ks], bf[ni],
                                                                acc[mi][ni], 0, 0, 0);
    }
    __builtin_amdgcn_s_setprio(0);
    // normalized P: nontemporal global write (write-only stream) + bf16 to LDS
    #pragma unroll
    for (int mi = 0; mi < 2; ++mi)
      #pragma unroll
      for (int ni = 0; ni < 4; ++ni)
        #pragma unroll
        for (int r = 0; r < 4; ++r) {
          int row = wv * 32 + mi * 16 + crow + r;
          float p = __expf(acc[mi][ni][r] - m_run[mi][r]) * inv_s[mi][r];
          __builtin_nontemporal_store(p, &az[(size_t)(m0 + row) * 1024 + c0 + ni * 16 + fr]);
          sP[row][ni * 16 + fr] = __float2bfloat16(p);
        }
    // sP is read only by the wave that wrote it (rows wv*32..+31): intra-wave
    // fence suffices. asm wait orders the ds_writes; sched_barrier stops the
    // compiler hoisting the sP reads above it (rule #18).
    asm volatile("s_waitcnt lgkmcnt(0)" ::: "memory");
    __builtin_amdgcn_sched_barrier(0);
    __builtin_amdgcn_s_setprio(1);
    #pragma unroll
    for (int ks = 0; ks < 2; ++ks) {
      short8 pa[2], vb[4];
      #pragma unroll
      for (int mi = 0; mi < 2; ++mi)
        pa[mi] = *(const short8*)(&sP[wv * 32 + mi * 16 + fr][ks * 32 + fk]);
      #pragma unroll
      for (int ni = 0; ni < 4; ++ni)
        vb[ni] = *(const short8*)(&sV[cur][ni * 16 + fr][ks * 32 + fk]);
      #pragma unroll
      for (int mi = 0; mi < 2; ++mi)
        #pragma unroll
        for (int ni = 0; ni < 4; ++ni)
          cacc[mi][ni] = __builtin_amdgcn_mfma_f32_16x16x32_bf16(pa[mi], vb[ni],
                                                                 cacc[mi][ni], 0, 0, 0);
    }
    __builtin_amdgcn_s_setprio(0);
    __syncthreads();                  // publishes K/V buffer cur^1 for next iter
  }

  // ctx write: [1024][64] bf16 per head
  #pragma unroll
  for (int mi = 0; mi < 2; ++mi)
    #pragma unroll
    for (int ni = 0; ni < 4; ++ni)
      #pragma unroll
      for (int r = 0; r < 4; ++r) {
        int row = wv * 32 + mi * 16 + crow + r;
        cz[(size_t)(m0 + row) * 64 + ni * 16 + fr] = __float2bfloat16(cacc[mi][ni][r]);
      }
}

// ---------------- row layernorm, width 1024, in place (+optional bf16 copy) -------
__global__ __launch_bounds__(256) void k_layernorm(float* __restrict__ io,
                                                   bf16_t* __restrict__ ob,
                                                   const float* __restrict__ g,
                                                   const float* __restrict__ bta) {
  float* r = io + (size_t)blockIdx.x * 1024;
  const int t = threadIdx.x;
  f32x4 x = *(const f32x4*)(r + t * 4);
  float s = x[0] + x[1] + x[2] + x[3];
  float s2 = x[0] * x[0] + x[1] * x[1] + x[2] * x[2] + x[3] * x[3];
  #pragma unroll
  for (int o = 32; o > 0; o >>= 1) { s += __shfl_xor(s, o, 64); s2 += __shfl_xor(s2, o, 64); }
  __shared__ float as[4], as2[4];
  if ((t & 63) == 0) { as[t >> 6] = s; as2[t >> 6] = s2; }
  __syncthreads();
  s = as[0] + as[1] + as[2] + as[3];
  s2 = as2[0] + as2[1] + as2[2] + as2[3];
  float mu = s * (1.0f / 1024.0f);
  float var = s2 * (1.0f / 1024.0f) - mu * mu;
  float rs = rsqrtf(var + 1e-5f);
  f32x4 gg = *(const f32x4*)(g + t * 4);
  f32x4 bb = *(const f32x4*)(bta + t * 4);
  f32x4 y;
  #pragma unroll
  for (int i = 0; i < 4; ++i) y[i] = (x[i] - mu) * rs * gg[i] + bb[i];
  *(f32x4*)(r + t * 4) = y;
  if (ob) {
    short4v o4;
    o4[0] = bfbits(y[0]); o4[1] = bfbits(y[1]); o4[2] = bfbits(y[2]); o4[3] = bfbits(y[3]);
    *(short4v*)((short*)ob + (size_t)blockIdx.x * 1024 + t * 4) = o4;
  }
}

extern "C" void kernel_launch(void* const* d_in, const int* in_sizes, int n_in,
                              void* d_out, int out_size, void* d_ws, size_t ws_size,
                              hipStream_t stream) {
  (void)in_sizes; (void)n_in; (void)out_size;
  const float* inputs = (const float*)d_in[0];
  const float* Wq = (const float*)d_in[1];  const float* bq = (const float*)d_in[2];
  const float* Wk = (const float*)d_in[3];  const float* bk = (const float*)d_in[4];
  const float* Wv = (const float*)d_in[5];  const float* bv = (const float*)d_in[6];
  const float* Wo = (const float*)d_in[7];  const float* bo = (const float*)d_in[8];
  const float* ln1g = (const float*)d_in[9];  const float* ln1b = (const float*)d_in[10];
  const float* W1 = (const float*)d_in[11]; const float* b1 = (const float*)d_in[12];
  const float* W2 = (const float*)d_in[13]; const float* b2 = (const float*)d_in[14];
  const float* ln2g = (const float*)d_in[15]; const float* ln2b = (const float*)d_in[16];

  const size_t MB = 1ull << 20;
  if (ws_size < 96 * MB) return;  // layout below needs 96 MB scratch

  char* ws = (char*)d_ws;
  bf16_t* WQT  = (bf16_t*)(ws + 0 * MB);   // [1024][1024]; WQT/WKT/WVT contiguous
  bf16_t* WKT  = (bf16_t*)(ws + 2 * MB);   //   -> fused QKV sees [3072][1024]
  bf16_t* WVT  = (bf16_t*)(ws + 4 * MB);
  bf16_t* WOT  = (bf16_t*)(ws + 6 * MB);
  bf16_t* W1T  = (bf16_t*)(ws + 8 * MB);   // [4096][1024]
  bf16_t* W2T  = (bf16_t*)(ws + 16 * MB);  // [1024][4096]
  bf16_t* XB   = (bf16_t*)(ws + 24 * MB);  // [4096][1024]; dead after QKV
  bf16_t* QB   = (bf16_t*)(ws + 32 * MB);  // QB/KB/VB contiguous, 8MB stride
  bf16_t* KB   = (bf16_t*)(ws + 40 * MB);
  bf16_t* VB   = (bf16_t*)(ws + 48 * MB);  // dead after Vt transpose
  bf16_t* VT   = (bf16_t*)(ws + 56 * MB);  // [64 batches][64][1024]; dead after flash
  bf16_t* CTX  = (bf16_t*)(ws + 24 * MB);  // reuse XB slot
  float*  OUT1F = (float*)(ws + 40 * MB);  // fp32 [4096][1024] (reuse KB+VB slots)
  bf16_t* OUT1B = (bf16_t*)(ws + 32 * MB); // reuse QB slot
  bf16_t* HB   = (bf16_t*)(ws + 64 * MB);  // [4096][4096]

  float* outF = (float*)d_out;             // [4096][1024]
  float* attn = outF + 4194304;            // [64][1024][1024] fp32 (final output region)

  // --- prep: bf16 input copy + transposed bf16 weights ---
  k_f32_to_bf16<<<4096, 256, 0, stream>>>(inputs, XB);
  k_transpose4_f32_bf16<<<dim3(32, 32, 4), 256, 0, stream>>>(Wq, Wk, Wv, Wo,
                                                             WQT, WKT, WVT, WOT);
  k_transpose_f32_bf16<<<dim3(128, 32), 256, 0, stream>>>(W1, W1T, 1024, 4096);
  k_transpose_f32_bf16<<<dim3(32, 128), 256, 0, stream>>>(W2, W2T, 4096, 1024);

  // --- fused QKV: [4096,1024] @ [1024,3072] -> QB/KB/VB (Q pre-scaled 1/8) ---
  k_gemm_bt<128, 128, false, true, false, false, false, true, true>
      <<<dim3(24, 32), 256, 0, stream>>>(XB, WQT, nullptr, QB, bq, bk, bv, nullptr,
                                         1024, 1024, 1024, 1024, 1.0f);

  // --- per-"head" V transpose: [1024][64] -> [64][1024], 64 batches ---
  k_transpose_bf16_b<<<dim3(2, 32, 64), 256, 0, stream>>>(VB, VT, 1024, 64, 65536, 65536);

  // --- fused scores+softmax+PV; writes exact attn fp32 + ctx bf16 ---
  k_flash_attn<<<dim3(8, 64), 256, 0, stream>>>(QB, KB, VT, attn, CTX);

  // --- out-proj + bias + residual(inputs) -> OUT1F fp32 (BN=64: 512 blocks) ---
  k_gemm_bt<128, 64, false, true, false, true, true, false, false>
      <<<dim3(16, 32), 256, 0, stream>>>(CTX, WOT, OUT1F, nullptr, bo, nullptr, nullptr,
                                         inputs, 1024, 1024, 1024, 1024, 1.0f);

  // --- LN1 in place + bf16 copy ---
  k_layernorm<<<4096, 256, 0, stream>>>(OUT1F, OUT1B, ln1g, ln1b);

  // --- FFN1: relu(out1 @ W1 + b1) -> HB bf16 [4096][4096] ---
  k_gemm_bt<128, 128, false, true, true, false, false, true, false>
      <<<dim3(32, 32), 256, 0, stream>>>(OUT1B, W1T, nullptr, HB, b1, nullptr, nullptr,
                                         nullptr, 1024, 1024, 1024, 4096, 1.0f);

  // --- FFN2: HB @ W2 + b2 + out1 -> d_out[0:4M] fp32 (BN=64: 512 blocks) ---
  k_gemm_bt<128, 64, false, true, false, true, true, false, false>
      <<<dim3(16, 32), 256, 0, stream>>>(HB, W2T, outF, nullptr, b2, nullptr, nullptr,
                                         OUT1F, 4096, 4096, 4096, 1024, 1.0f);

  // --- LN2 in place on d_out ---
  k_layernorm<<<4096, 256, 0, stream>>>(outF, nullptr, ln2g, ln2b);
}

// Round 5
// 645.199 us; speedup vs baseline: 1.1813x; 1.0328x over previous
//
#include <hip/hip_runtime.h>
#include <hip/hip_bf16.h>
#include <stdint.h>

// EncoderLayer on MI355X: bf16 MFMA GEMMs + fp32 softmax/LN epilogues.
// Pipeline: prep(convert/transpose) -> fused QKV (Q pre-scaled 1/8) -> Vt ->
//           flash(scores+softmax+PV, writes exact attn) -> Wo+resid -> LN1 ->
//           FFN1(relu) -> FFN2+resid -> LN2.
// GEMM: global_load_lds width=16 staging (m97), T1 XCD swizzle (grids %8==0).
// Flash: 48KB LDS (XOR-swizzled, 3 blocks/CU), per-lane online softmax stats
//        (no per-chunk shuffles), head-grouped XCD swizzle for K/V L2 reuse.

using bf16_t  = __hip_bfloat16;
using short8  = __attribute__((ext_vector_type(8))) short;
using short4v = __attribute__((ext_vector_type(4))) short;
using f32x4   = __attribute__((ext_vector_type(4))) float;

#define DEV static __device__ __forceinline__

DEV short bfbits(float f) {
  bf16_t h = __float2bfloat16(f);
  union { bf16_t h; short s; } u; u.h = h; return u.s;
}

// async global->LDS, 16 bytes per lane; lds must be wave-uniform, HW writes
// lds + lane*16 (cdna_hip_programming.md §5: width=16 = 874 TF lever).
DEV void gload_lds16(const bf16_t* g, bf16_t* lds) {
  __builtin_amdgcn_global_load_lds(
      (const __attribute__((address_space(1))) void*)g,
      (__attribute__((address_space(3))) void*)lds, 16, 0, 0);
}

// ---------------- elementwise fp32 -> bf16 (4 elems/thread) ----------------
__global__ __launch_bounds__(256) void k_f32_to_bf16(const float* __restrict__ in,
                                                     bf16_t* __restrict__ out) {
  size_t i = ((size_t)blockIdx.x * 256 + threadIdx.x) * 4;
  f32x4 x = *(const f32x4*)(in + i);
  short4v o;
  o[0] = bfbits(x[0]); o[1] = bfbits(x[1]); o[2] = bfbits(x[2]); o[3] = bfbits(x[3]);
  *(short4v*)((short*)out + i) = o;
}

// ---------------- transpose fp32 [R][C] -> bf16 [C][R] ----------------
__global__ __launch_bounds__(256) void k_transpose_f32_bf16(const float* __restrict__ in,
                                                            bf16_t* __restrict__ out,
                                                            int R, int C) {
  __shared__ float tile[32][33];
  int tx = threadIdx.x & 31, ty = threadIdx.x >> 5;   // 32 x 8
  int r0 = blockIdx.y * 32, c0 = blockIdx.x * 32;
  #pragma unroll
  for (int i = 0; i < 4; ++i)
    tile[ty + i * 8][tx] = in[(size_t)(r0 + ty + i * 8) * C + c0 + tx];
  __syncthreads();
  #pragma unroll
  for (int i = 0; i < 4; ++i)
    out[(size_t)(c0 + ty + i * 8) * R + r0 + tx] = __float2bfloat16(tile[tx][ty + i * 8]);
}

// ---- four square 1024x1024 transposes in one launch (z selects weight) ----
__global__ __launch_bounds__(256) void k_transpose4_f32_bf16(
    const float* __restrict__ w0, const float* __restrict__ w1,
    const float* __restrict__ w2, const float* __restrict__ w3,
    bf16_t* __restrict__ o0, bf16_t* __restrict__ o1,
    bf16_t* __restrict__ o2, bf16_t* __restrict__ o3) {
  __shared__ float tile[32][33];
  const int zz = blockIdx.z;
  const float* in = zz == 0 ? w0 : zz == 1 ? w1 : zz == 2 ? w2 : w3;
  bf16_t* out = zz == 0 ? o0 : zz == 1 ? o1 : zz == 2 ? o2 : o3;
  int tx = threadIdx.x & 31, ty = threadIdx.x >> 5;
  int r0 = blockIdx.y * 32, c0 = blockIdx.x * 32;
  #pragma unroll
  for (int i = 0; i < 4; ++i)
    tile[ty + i * 8][tx] = in[(size_t)(r0 + ty + i * 8) * 1024 + c0 + tx];
  __syncthreads();
  #pragma unroll
  for (int i = 0; i < 4; ++i)
    out[(size_t)(c0 + ty + i * 8) * 1024 + r0 + tx] = __float2bfloat16(tile[tx][ty + i * 8]);
}

// ---------------- batched transpose bf16 [R][C] -> [C][R] ----------------
__global__ __launch_bounds__(256) void k_transpose_bf16_b(const bf16_t* __restrict__ in,
                                                          bf16_t* __restrict__ out,
                                                          int R, int C, long sIn, long sOut) {
  __shared__ bf16_t tile[32][33];
  const bf16_t* inz = in + (size_t)blockIdx.z * sIn;
  bf16_t* outz = out + (size_t)blockIdx.z * sOut;
  int tx = threadIdx.x & 31, ty = threadIdx.x >> 5;
  int r0 = blockIdx.y * 32, c0 = blockIdx.x * 32;
  #pragma unroll
  for (int i = 0; i < 4; ++i)
    tile[ty + i * 8][tx] = inz[(size_t)(r0 + ty + i * 8) * C + c0 + tx];
  __syncthreads();
  #pragma unroll
  for (int i = 0; i < 4; ++i)
    outz[(size_t)(c0 + ty + i * 8) * R + r0 + tx] = tile[tx][ty + i * 8];
}

// ---------------- GEMM: C[M][N] = A[M][K](bf16) @ Bt[N][K](bf16) ----------------
// m97 structure: block 256 thr = 4 waves (2x2), wave tile (BM/2)x(BN/2),
// MFMA 16x16x32, BK=32, LINEAR LDS staged via global_load_lds width 16.
// T1: bijective XCD swizzle of linear block id (REQUIRES grid total %8==0).
// A-frag: A[m=lane&15][k=(lane>>4)*8+j]; C/D: col=lane&15, row=(lane>>4)*4+reg.
// QKV3: Bt is 3 vertically-concatenated [1024][K] weights; output routed to
// Cb + (n0>>10)*4194304 with per-tensor bias; Q (tz==0) pre-scaled by 1/8.
template<int BM, int BN, bool ALPHA, bool BIAS, bool RELU, bool RESID,
         bool OUTF, bool OUTB, bool QKV3>
__global__ __launch_bounds__(256)
void k_gemm_bt(const bf16_t* __restrict__ A, const bf16_t* __restrict__ Bt,
               float* __restrict__ Cf, bf16_t* __restrict__ Cb,
               const float* __restrict__ bias, const float* __restrict__ bias2,
               const float* __restrict__ bias3, const float* __restrict__ resid,
               int Kdim, int lda, int ldb, int ldc, float alpha) {
  constexpr int BK = 32;
  constexpr int WTM = BM / 2, WTN = BN / 2;
  constexpr int MI = WTM / 16, NI = WTN / 16;
  __shared__ __align__(16) bf16_t sA[BM * BK];
  __shared__ __align__(16) bf16_t sB[BN * BK];

  const int tid = threadIdx.x;
  const int lane = tid & 63;
  const int wv = tid >> 6;
  const int wm = wv & 1, wn = wv >> 1;

  // T1 XCD swizzle (bijective since total %8 == 0 for all call sites)
  const int gx = gridDim.x;
  const int total = gx * gridDim.y;
  const int lin = blockIdx.y * gx + blockIdx.x;
  const int swz = (lin & 7) * (total >> 3) + (lin >> 3);
  const size_t m0 = (size_t)(swz / gx) * BM;
  const size_t n0 = (size_t)(swz % gx) * BN;

  f32x4 acc[MI][NI] = {};

  // staging geometry: chunk = 16 rows = 1KB; lane l covers (row l>>2, 16B col l&3)
  const int rr = lane >> 2, cc = (lane & 3) * 8;
  const bf16_t* Arow = A + (m0 + rr) * (size_t)lda + cc;   // + chunk*16*lda + k0
  const bf16_t* Brow = Bt + (n0 + rr) * (size_t)ldb + cc;

  const int fm = wm * WTM + (lane & 15);
  const int fn = wn * WTN + (lane & 15);
  const int fk = (lane >> 4) * 8;

  for (int k0 = 0; k0 < Kdim; k0 += BK) {
    #pragma unroll
    for (int j = 0; j < BM / 64; ++j) {
      int c = j * 4 + wv;                       // chunk id, wave-uniform
      gload_lds16(Arow + (size_t)c * 16 * lda + k0, sA + c * 512);
    }
    #pragma unroll
    for (int j = 0; j < BN / 64; ++j) {
      int c = j * 4 + wv;
      gload_lds16(Brow + (size_t)c * 16 * ldb + k0, sB + c * 512);
    }
    __syncthreads();   // drains vmcnt: LDS tiles complete

    short8 av[MI], bvv[NI];
    #pragma unroll
    for (int mi = 0; mi < MI; ++mi) av[mi] = *(const short8*)(sA + (fm + mi * 16) * BK + fk);
    #pragma unroll
    for (int ni = 0; ni < NI; ++ni) bvv[ni] = *(const short8*)(sB + (fn + ni * 16) * BK + fk);
    #pragma unroll
    for (int mi = 0; mi < MI; ++mi)
      #pragma unroll
      for (int ni = 0; ni < NI; ++ni)
        acc[mi][ni] = __builtin_amdgcn_mfma_f32_16x16x32_bf16(av[mi], bvv[ni],
                                                              acc[mi][ni], 0, 0, 0);
    __syncthreads();
  }

  // epilogue
  const int tz = QKV3 ? (int)(n0 >> 10) : 0;                    // uniform per block
  const float* bp = BIAS ? (QKV3 ? (tz == 0 ? bias : (tz == 1 ? bias2 : bias3))
                                 : bias) : nullptr;
  bf16_t* cb = QKV3 ? (Cb + (size_t)tz * 4194304) : Cb;
  const float qscale = (QKV3 && tz == 0) ? 0.125f : 1.0f;
  const int col0 = (int)n0 + wn * WTN + (lane & 15);
  const int row0 = (int)m0 + wm * WTM + ((lane >> 4) << 2);
  #pragma unroll
  for (int ni = 0; ni < NI; ++ni) {
    const int col = col0 + ni * 16;
    const int colw = QKV3 ? (col & 1023) : col;
    const float bval = BIAS ? bp[colw] : 0.0f;
    #pragma unroll
    for (int mi = 0; mi < MI; ++mi) {
      #pragma unroll
      for (int r = 0; r < 4; ++r) {
        int row = row0 + mi * 16 + r;
        float v = acc[mi][ni][r];
        if (ALPHA) v *= alpha;
        v += bval;
        if (QKV3) v *= qscale;
        size_t off = (size_t)row * ldc + colw;
        if (RESID) v += resid[off];
        if (RELU) v = fmaxf(v, 0.0f);
        if (OUTF) Cf[off] = v;
        if (OUTB) cb[off] = __float2bfloat16(v);
      }
    }
  }
}

// ---------------- fused attention: S=(Q/8)@K^T, softmax (exact, written to
// attn), ctx = P @ V. One block = 128 Q-rows of one head; 4 waves, each wave
// owns 32 rows. Two passes (stats, emit+PV), S recomputed.
// Pass 1 stats are PER-LANE online (no per-chunk cross-lane shuffles); one
// 4-step shfl_xor merge after the pass. Q lives in registers (no sQ).
// LDS: 48KB linear [64]-wide sK/sV/sP with T2 XOR swizzle col^=(row&7)<<3
// (conflict-free ds_read_b128; 3 blocks/CU). Head-grouped XCD swizzle keeps
// each head's K/V on one XCD's L2. attn stores nontemporal.
__global__ __launch_bounds__(256) void k_flash_attn(const bf16_t* __restrict__ Qb,
                                                    const bf16_t* __restrict__ Kb,
                                                    const bf16_t* __restrict__ Vt,
                                                    float* __restrict__ attn,
                                                    bf16_t* __restrict__ ctx) {
  __shared__ __align__(16) bf16_t sK[2][64][64];
  __shared__ __align__(16) bf16_t sV[2][64][64];
  __shared__ __align__(16) bf16_t sP[128][64];

  const int tid = threadIdx.x;
  const int lane = tid & 63;
  const int wv = tid >> 6;            // wave owns rows wv*32 .. wv*32+31

  // XCD swizzle: grid (8,64), 512 blocks; XCD k gets heads k*8..k*8+7 whole.
  const int lin = blockIdx.y * 8 + blockIdx.x;
  const int swz = (lin & 7) * 64 + (lin >> 3);
  const int z = swz >> 3;
  const int m0 = (swz & 7) * 128;

  const bf16_t* Qz = Qb + (size_t)z * 65536;
  const bf16_t* Kz = Kb + (size_t)z * 65536;
  const bf16_t* Vz = Vt + (size_t)z * 65536;
  float* az = attn + (size_t)z * 1048576;
  bf16_t* cz = ctx + (size_t)z * 65536;

  // staging geometry: thread covers rows j*32 + (tid>>3), 16B col (tid&7)*8.
  // LDS col is XOR-swizzled: scx = sc ^ ((row&7)<<3); row&7 == sr&7 here.
  const int sr = tid >> 3, sc = (tid & 7) * 8;
  const int scx = sc ^ ((sr & 7) << 3);

  const int fr = lane & 15;           // frag row/col index
  const int fk = (lane >> 4) * 8;     // frag k offset
  const int crow = (lane >> 4) << 2;  // C/D row base
  const int rko = (fr & 7) << 3;      // read-side XOR for rows ≡ fr (mod 8)

  // Q A-frags straight from global (one-time; Q pre-scaled by 1/8 upstream)
  short8 qf[2][2];
  #pragma unroll
  for (int mi = 0; mi < 2; ++mi)
    #pragma unroll
    for (int ks = 0; ks < 2; ++ks)
      qf[mi][ks] = *(const short8*)(Qz + (size_t)(m0 + wv * 32 + mi * 16 + fr) * 64 +
                                    ks * 32 + fk);

  float m_ln[2][4], s_ln[2][4];       // per-lane online stats (cols ni*16+fr)
  #pragma unroll
  for (int mi = 0; mi < 2; ++mi)
    #pragma unroll
    for (int r = 0; r < 4; ++r) { m_ln[mi][r] = -1e30f; s_ln[mi][r] = 0.0f; }

  short8 kreg[2], vreg[2];

  // ---- pass 1: per-lane online max/sum-exp over all 16 K-chunks ----
  #pragma unroll
  for (int j = 0; j < 2; ++j)
    kreg[j] = *(const short8*)(Kz + (size_t)(j * 32 + sr) * 64 + sc);
  #pragma unroll
  for (int j = 0; j < 2; ++j)
    *(short8*)(&sK[0][j * 32 + sr][scx]) = kreg[j];
  #pragma unroll
  for (int j = 0; j < 2; ++j)
    kreg[j] = *(const short8*)(Kz + (size_t)(64 + j * 32 + sr) * 64 + sc);
  __syncthreads();

  for (int c = 0; c < 16; ++c) {
    const int cur = c & 1;
    if (c + 1 < 16) {                 // publish chunk c+1 (buffer cur^1)
      #pragma unroll
      for (int j = 0; j < 2; ++j)
        *(short8*)(&sK[cur ^ 1][j * 32 + sr][scx]) = kreg[j];
    }
    if (c + 2 < 16) {                 // prefetch chunk c+2 under MFMA+stats
      #pragma unroll
      for (int j = 0; j < 2; ++j)
        kreg[j] = *(const short8*)(Kz + (size_t)((c + 2) * 64 + j * 32 + sr) * 64 + sc);
    }
    f32x4 acc[2][4] = {};
    __builtin_amdgcn_s_setprio(1);
    #pragma unroll
    for (int ks = 0; ks < 2; ++ks) {
      short8 bf[4];
      #pragma unroll
      for (int ni = 0; ni < 4; ++ni)
        bf[ni] = *(const short8*)(&sK[cur][ni * 16 + fr][(ks * 32 + fk) ^ rko]);
      #pragma unroll
      for (int mi = 0; mi < 2; ++mi)
        #pragma unroll
        for (int ni = 0; ni < 4; ++ni)
          acc[mi][ni] = __builtin_amdgcn_mfma_f32_16x16x32_bf16(qf[mi][ks], bf[ni],
                                                                acc[mi][ni], 0, 0, 0);
    }
    __builtin_amdgcn_s_setprio(0);
    // per-lane online update: no cross-lane traffic inside the chunk loop
    #pragma unroll
    for (int mi = 0; mi < 2; ++mi)
      #pragma unroll
      for (int r = 0; r < 4; ++r) {
        float cm = fmaxf(fmaxf(acc[mi][0][r], acc[mi][1][r]),
                         fmaxf(acc[mi][2][r], acc[mi][3][r]));
        float mo = m_ln[mi][r];
        float mn = fmaxf(mo, cm);
        float se = 0.0f;
        #pragma unroll
        for (int ni = 0; ni < 4; ++ni) se += __expf(acc[mi][ni][r] - mn);
        s_ln[mi][r] = s_ln[mi][r] * __expf(mo - mn) + se;
        m_ln[mi][r] = mn;
      }
    __syncthreads();                  // buffer cur^1 now visible for next iter
  }

  // one cross-lane merge over the 16-lane fr group (log-sum-exp combine)
  float m_run[2][4], inv_s[2][4];
  #pragma unroll
  for (int mi = 0; mi < 2; ++mi)
    #pragma unroll
    for (int r = 0; r < 4; ++r) {
      float m = m_ln[mi][r], s = s_ln[mi][r];
      #pragma unroll
      for (int o = 1; o < 16; o <<= 1) {
        float m2 = __shfl_xor(m, o, 64);
        float s2 = __shfl_xor(s, o, 64);
        float mn = fmaxf(m, m2);
        s = s * __expf(m - mn) + s2 * __expf(m2 - mn);
        m = mn;
      }
      m_run[mi][r] = m;
      inv_s[mi][r] = 1.0f / s;
    }

  // ---- pass 2: recompute S, emit exact softmax to attn, accumulate P@V ----
  #pragma unroll
  for (int j = 0; j < 2; ++j) {
    kreg[j] = *(const short8*)(Kz + (size_t)(j * 32 + sr) * 64 + sc);
    vreg[j] = *(const short8*)(Vz + (size_t)(j * 32 + sr) * 1024 + sc);
  }
  #pragma unroll
  for (int j = 0; j < 2; ++j) {
    *(short8*)(&sK[0][j * 32 + sr][scx]) = kreg[j];
    *(short8*)(&sV[0][j * 32 + sr][scx]) = vreg[j];
  }
  #pragma unroll
  for (int j = 0; j < 2; ++j) {
    kreg[j] = *(const short8*)(Kz + (size_t)(64 + j * 32 + sr) * 64 + sc);
    vreg[j] = *(const short8*)(Vz + (size_t)(j * 32 + sr) * 1024 + 64 + sc);
  }
  __syncthreads();

  f32x4 cacc[2][4] = {};
  for (int c = 0; c < 16; ++c) {
    const int cur = c & 1;
    const int c0 = c * 64;
    if (c + 1 < 16) {
      #pragma unroll
      for (int j = 0; j < 2; ++j) {
        *(short8*)(&sK[cur ^ 1][j * 32 + sr][scx]) = kreg[j];
        *(short8*)(&sV[cur ^ 1][j * 32 + sr][scx]) = vreg[j];
      }
    }
    if (c + 2 < 16) {
      #pragma unroll
      for (int j = 0; j < 2; ++j) {
        kreg[j] = *(const short8*)(Kz + (size_t)((c + 2) * 64 + j * 32 + sr) * 64 + sc);
        vreg[j] = *(const short8*)(Vz + (size_t)(j * 32 + sr) * 1024 + (c + 2) * 64 + sc);
      }
    }
    f32x4 acc[2][4] = {};
    __builtin_amdgcn_s_setprio(1);
    #pragma unroll
    for (int ks = 0; ks < 2; ++ks) {
      short8 bf[4];
      #pragma unroll
      for (int ni = 0; ni < 4; ++ni)
        bf[ni] = *(const short8*)(&sK[cur][ni * 16 + fr][(ks * 32 + fk) ^ rko]);
      #pragma unroll
      for (int mi = 0; mi < 2; ++mi)
        #pragma unroll
        for (int ni = 0; ni < 4; ++ni)
          acc[mi][ni] = __builtin_amdgcn_mfma_f32_16x16x32_bf16(qf[mi][ks], bf[ni],
                                                                acc[mi][ni], 0, 0, 0);
    }
    __builtin_amdgcn_s_setprio(0);
    // normalized P: nontemporal global write (write-only stream) + bf16 to LDS
    #pragma unroll
    for (int mi = 0; mi < 2; ++mi)
      #pragma unroll
      for (int ni = 0; ni < 4; ++ni)
        #pragma unroll
        for (int r = 0; r < 4; ++r) {
          int row = wv * 32 + mi * 16 + crow + r;
          float p = __expf(acc[mi][ni][r] - m_run[mi][r]) * inv_s[mi][r];
          __builtin_nontemporal_store(p, &az[(size_t)(m0 + row) * 1024 + c0 + ni * 16 + fr]);
          sP[row][(ni * 16 + fr) ^ (((crow + r) & 7) << 3)] = __float2bfloat16(p);
        }
    // sP is read only by the wave that wrote it: intra-wave fence suffices.
    // asm wait orders the ds_writes; sched_barrier stops the compiler hoisting
    // the sP reads above it (rule #18).
    asm volatile("s_waitcnt lgkmcnt(0)" ::: "memory");
    __builtin_amdgcn_sched_barrier(0);
    __builtin_amdgcn_s_setprio(1);
    #pragma unroll
    for (int ks = 0; ks < 2; ++ks) {
      short8 pa[2], vb[4];
      #pragma unroll
      for (int mi = 0; mi < 2; ++mi)
        pa[mi] = *(const short8*)(&sP[wv * 32 + mi * 16 + fr][(ks * 32 + fk) ^ rko]);
      #pragma unroll
      for (int ni = 0; ni < 4; ++ni)
        vb[ni] = *(const short8*)(&sV[cur][ni * 16 + fr][(ks * 32 + fk) ^ rko]);
      #pragma unroll
      for (int mi = 0; mi < 2; ++mi)
        #pragma unroll
        for (int ni = 0; ni < 4; ++ni)
          cacc[mi][ni] = __builtin_amdgcn_mfma_f32_16x16x32_bf16(pa[mi], vb[ni],
                                                                 cacc[mi][ni], 0, 0, 0);
    }
    __builtin_amdgcn_s_setprio(0);
    __syncthreads();                  // publishes K/V buffer cur^1 for next iter
  }

  // ctx write: [1024][64] bf16 per head
  #pragma unroll
  for (int mi = 0; mi < 2; ++mi)
    #pragma unroll
    for (int ni = 0; ni < 4; ++ni)
      #pragma unroll
      for (int r = 0; r < 4; ++r) {
        int row = wv * 32 + mi * 16 + crow + r;
        cz[(size_t)(m0 + row) * 64 + ni * 16 + fr] = __float2bfloat16(cacc[mi][ni][r]);
      }
}

// ---------------- row layernorm, width 1024, in place (+optional bf16 copy) -------
__global__ __launch_bounds__(256) void k_layernorm(float* __restrict__ io,
                                                   bf16_t* __restrict__ ob,
                                                   const float* __restrict__ g,
                                                   const float* __restrict__ bta) {
  float* r = io + (size_t)blockIdx.x * 1024;
  const int t = threadIdx.x;
  f32x4 x = *(const f32x4*)(r + t * 4);
  float s = x[0] + x[1] + x[2] + x[3];
  float s2 = x[0] * x[0] + x[1] * x[1] + x[2] * x[2] + x[3] * x[3];
  #pragma unroll
  for (int o = 32; o > 0; o >>= 1) { s += __shfl_xor(s, o, 64); s2 += __shfl_xor(s2, o, 64); }
  __shared__ float as[4], as2[4];
  if ((t & 63) == 0) { as[t >> 6] = s; as2[t >> 6] = s2; }
  __syncthreads();
  s = as[0] + as[1] + as[2] + as[3];
  s2 = as2[0] + as2[1] + as2[2] + as2[3];
  float mu = s * (1.0f / 1024.0f);
  float var = s2 * (1.0f / 1024.0f) - mu * mu;
  float rs = rsqrtf(var + 1e-5f);
  f32x4 gg = *(const f32x4*)(g + t * 4);
  f32x4 bb = *(const f32x4*)(bta + t * 4);
  f32x4 y;
  #pragma unroll
  for (int i = 0; i < 4; ++i) y[i] = (x[i] - mu) * rs * gg[i] + bb[i];
  *(f32x4*)(r + t * 4) = y;
  if (ob) {
    short4v o4;
    o4[0] = bfbits(y[0]); o4[1] = bfbits(y[1]); o4[2] = bfbits(y[2]); o4[3] = bfbits(y[3]);
    *(short4v*)((short*)ob + (size_t)blockIdx.x * 1024 + t * 4) = o4;
  }
}

extern "C" void kernel_launch(void* const* d_in, const int* in_sizes, int n_in,
                              void* d_out, int out_size, void* d_ws, size_t ws_size,
                              hipStream_t stream) {
  (void)in_sizes; (void)n_in; (void)out_size;
  const float* inputs = (const float*)d_in[0];
  const float* Wq = (const float*)d_in[1];  const float* bq = (const float*)d_in[2];
  const float* Wk = (const float*)d_in[3];  const float* bk = (const float*)d_in[4];
  const float* Wv = (const float*)d_in[5];  const float* bv = (const float*)d_in[6];
  const float* Wo = (const float*)d_in[7];  const float* bo = (const float*)d_in[8];
  const float* ln1g = (const float*)d_in[9];  const float* ln1b = (const float*)d_in[10];
  const float* W1 = (const float*)d_in[11]; const float* b1 = (const float*)d_in[12];
  const float* W2 = (const float*)d_in[13]; const float* b2 = (const float*)d_in[14];
  const float* ln2g = (const float*)d_in[15]; const float* ln2b = (const float*)d_in[16];

  const size_t MB = 1ull << 20;
  if (ws_size < 96 * MB) return;  // layout below needs 96 MB scratch

  char* ws = (char*)d_ws;
  bf16_t* WQT  = (bf16_t*)(ws + 0 * MB);   // [1024][1024]; WQT/WKT/WVT contiguous
  bf16_t* WKT  = (bf16_t*)(ws + 2 * MB);   //   -> fused QKV sees [3072][1024]
  bf16_t* WVT  = (bf16_t*)(ws + 4 * MB);
  bf16_t* WOT  = (bf16_t*)(ws + 6 * MB);
  bf16_t* W1T  = (bf16_t*)(ws + 8 * MB);   // [4096][1024]
  bf16_t* W2T  = (bf16_t*)(ws + 16 * MB);  // [1024][4096]
  bf16_t* XB   = (bf16_t*)(ws + 24 * MB);  // [4096][1024]; dead after QKV
  bf16_t* QB   = (bf16_t*)(ws + 32 * MB);  // QB/KB/VB contiguous, 8MB stride
  bf16_t* KB   = (bf16_t*)(ws + 40 * MB);
  bf16_t* VB   = (bf16_t*)(ws + 48 * MB);  // dead after Vt transpose
  bf16_t* VT   = (bf16_t*)(ws + 56 * MB);  // [64 batches][64][1024]; dead after flash
  bf16_t* CTX  = (bf16_t*)(ws + 24 * MB);  // reuse XB slot
  float*  OUT1F = (float*)(ws + 40 * MB);  // fp32 [4096][1024] (reuse KB+VB slots)
  bf16_t* OUT1B = (bf16_t*)(ws + 32 * MB); // reuse QB slot
  bf16_t* HB   = (bf16_t*)(ws + 64 * MB);  // [4096][4096]

  float* outF = (float*)d_out;             // [4096][1024]
  float* attn = outF + 4194304;            // [64][1024][1024] fp32 (final output region)

  // --- prep: bf16 input copy + transposed bf16 weights ---
  k_f32_to_bf16<<<4096, 256, 0, stream>>>(inputs, XB);
  k_transpose4_f32_bf16<<<dim3(32, 32, 4), 256, 0, stream>>>(Wq, Wk, Wv, Wo,
                                                             WQT, WKT, WVT, WOT);
  k_transpose_f32_bf16<<<dim3(128, 32), 256, 0, stream>>>(W1, W1T, 1024, 4096);
  k_transpose_f32_bf16<<<dim3(32, 128), 256, 0, stream>>>(W2, W2T, 4096, 1024);

  // --- fused QKV: [4096,1024] @ [1024,3072] -> QB/KB/VB (Q pre-scaled 1/8) ---
  k_gemm_bt<128, 128, false, true, false, false, false, true, true>
      <<<dim3(24, 32), 256, 0, stream>>>(XB, WQT, nullptr, QB, bq, bk, bv, nullptr,
                                         1024, 1024, 1024, 1024, 1.0f);

  // --- per-"head" V transpose: [1024][64] -> [64][1024], 64 batches ---
  k_transpose_bf16_b<<<dim3(2, 32, 64), 256, 0, stream>>>(VB, VT, 1024, 64, 65536, 65536);

  // --- fused scores+softmax+PV; writes exact attn fp32 + ctx bf16 ---
  k_flash_attn<<<dim3(8, 64), 256, 0, stream>>>(QB, KB, VT, attn, CTX);

  // --- out-proj + bias + residual(inputs) -> OUT1F fp32 (BN=64: 512 blocks) ---
  k_gemm_bt<128, 64, false, true, false, true, true, false, false>
      <<<dim3(16, 32), 256, 0, stream>>>(CTX, WOT, OUT1F, nullptr, bo, nullptr, nullptr,
                                         inputs, 1024, 1024, 1024, 1024, 1.0f);

  // --- LN1 in place + bf16 copy ---
  k_layernorm<<<4096, 256, 0, stream>>>(OUT1F, OUT1B, ln1g, ln1b);

  // --- FFN1: relu(out1 @ W1 + b1) -> HB bf16 [4096][4096] ---
  k_gemm_bt<128, 128, false, true, true, false, false, true, false>
      <<<dim3(32, 32), 256, 0, stream>>>(OUT1B, W1T, nullptr, HB, b1, nullptr, nullptr,
                                         nullptr, 1024, 1024, 1024, 4096, 1.0f);

  // --- FFN2: HB @ W2 + b2 + out1 -> d_out[0:4M] fp32 (BN=64: 512 blocks) ---
  k_gemm_bt<128, 64, false, true, false, true, true, false, false>
      <<<dim3(16, 32), 256, 0, stream>>>(HB, W2T, outF, nullptr, b2, nullptr, nullptr,
                                         OUT1F, 4096, 4096, 4096, 1024, 1.0f);

  // --- LN2 in place on d_out ---
  k_layernorm<<<4096, 256, 0, stream>>>(outF, nullptr, ln2g, ln2b);
}